// Round 1
// baseline (2570.053 us; speedup 1.0000x reference)
//
#include <hip/hip_runtime.h>
#include <math.h>

#define GS 132  // LDS row stride (floats) for GEMM tiles: 132%8==4 -> conflict-free row strides

// ---------------- row L2-normalize: out[r] = in[r]/||in[r]|| ----------------
__global__ __launch_bounds__(256) void k_norm(const float* __restrict__ in,
                                              float* __restrict__ out, int R) {
  int g = (blockIdx.x * 256 + threadIdx.x) >> 6;
  int lane = threadIdx.x & 63;
  if (g >= R) return;
  float2 v = ((const float2*)(in + (size_t)g * 128))[lane];
  float ss = v.x * v.x + v.y * v.y;
#pragma unroll
  for (int o = 32; o; o >>= 1) ss += __shfl_xor(ss, o, 64);
  float s = 1.0f / sqrtf(ss);
  ((float2*)(out + (size_t)g * 128))[lane] = make_float2(v.x * s, v.y * s);
}

// ---------------- 128x128 transpose ----------------
__global__ __launch_bounds__(256) void k_t128(const float* __restrict__ in,
                                              float* __restrict__ out) {
  for (int i = threadIdx.x; i < 128 * 128; i += 256) {
    int k = i >> 7, j = i & 127;
    out[j * 128 + k] = in[i];
  }
}

// ---------------- generic C[MxN] = A[Mx128] @ B[Nx128]^T ----------------
__global__ __launch_bounds__(256) void k_gemm_abt(const float* __restrict__ A,
                                                  const float* __restrict__ B,
                                                  float* __restrict__ C, int M, int N) {
  __shared__ float As[64][GS];
  __shared__ float Bs[48][GS];
  const int t = threadIdx.x;
  const int m0 = blockIdx.y * 64, n0 = blockIdx.x * 48;
  for (int i = t; i < 64 * 32; i += 256) {
    int r = i >> 5, c4 = (i & 31) << 2;
    float4 v = make_float4(0.f, 0.f, 0.f, 0.f);
    if (m0 + r < M) v = *(const float4*)(A + (size_t)(m0 + r) * 128 + c4);
    *(float4*)&As[r][c4] = v;
  }
  for (int i = t; i < 48 * 32; i += 256) {
    int r = i >> 5, c4 = (i & 31) << 2;
    float4 v = make_float4(0.f, 0.f, 0.f, 0.f);
    if (n0 + r < N) v = *(const float4*)(B + (size_t)(n0 + r) * 128 + c4);
    *(float4*)&Bs[r][c4] = v;
  }
  __syncthreads();
  const int ty = t >> 4, tx = t & 15;
  float acc[4][3];
#pragma unroll
  for (int i = 0; i < 4; i++)
#pragma unroll
    for (int j = 0; j < 3; j++) acc[i][j] = 0.f;
#pragma unroll 4
  for (int k = 0; k < 128; k += 4) {
    float4 a[4], b[3];
#pragma unroll
    for (int i = 0; i < 4; i++) a[i] = *(const float4*)&As[ty + 16 * i][k];
#pragma unroll
    for (int j = 0; j < 3; j++) b[j] = *(const float4*)&Bs[tx + 16 * j][k];
#pragma unroll
    for (int i = 0; i < 4; i++)
#pragma unroll
      for (int j = 0; j < 3; j++) {
        float s = acc[i][j];
        s = fmaf(a[i].x, b[j].x, s);
        s = fmaf(a[i].y, b[j].y, s);
        s = fmaf(a[i].z, b[j].z, s);
        s = fmaf(a[i].w, b[j].w, s);
        acc[i][j] = s;
      }
  }
#pragma unroll
  for (int i = 0; i < 4; i++) {
    int m = m0 + ty + 16 * i;
    if (m >= M) continue;
#pragma unroll
    for (int j = 0; j < 3; j++) {
      int n = n0 + tx + 16 * j;
      if (n < N) C[(size_t)m * N + n] = acc[i][j];
    }
  }
}

// ---------------- sim = P @ CK^T (fused top-3 over 1024 intents) ----------------
__global__ __launch_bounds__(256) void k_sim_top3(const float* __restrict__ P,
                                                  const float* __restrict__ CK,
                                                  int* __restrict__ idx3, int M) {
  __shared__ float As[64][GS];
  __shared__ float Bs[48][GS];
  const int t = threadIdx.x;
  const int m0 = blockIdx.x * 64;
  for (int i = t; i < 64 * 32; i += 256) {
    int r = i >> 5, c4 = (i & 31) << 2;
    float4 v = make_float4(0.f, 0.f, 0.f, 0.f);
    if (m0 + r < M) v = *(const float4*)(P + (size_t)(m0 + r) * 128 + c4);
    *(float4*)&As[r][c4] = v;
  }
  const int ty = t >> 4, tx = t & 15;
  float tv[4][3];
  int tc[4][3];
#pragma unroll
  for (int i = 0; i < 4; i++)
#pragma unroll
    for (int j = 0; j < 3; j++) { tv[i][j] = -INFINITY; tc[i][j] = 0; }

  for (int nt = 0; nt < 22; nt++) {
    int n0 = nt * 48;
    __syncthreads();
    for (int i = t; i < 48 * 32; i += 256) {
      int r = i >> 5, c4 = (i & 31) << 2;
      float4 v = make_float4(0.f, 0.f, 0.f, 0.f);
      if (n0 + r < 1024) v = *(const float4*)(CK + (size_t)(n0 + r) * 128 + c4);
      *(float4*)&Bs[r][c4] = v;
    }
    __syncthreads();
    float acc[4][3];
#pragma unroll
    for (int i = 0; i < 4; i++)
#pragma unroll
      for (int j = 0; j < 3; j++) acc[i][j] = 0.f;
#pragma unroll 4
    for (int k = 0; k < 128; k += 4) {
      float4 a[4], b[3];
#pragma unroll
      for (int i = 0; i < 4; i++) a[i] = *(const float4*)&As[ty + 16 * i][k];
#pragma unroll
      for (int j = 0; j < 3; j++) b[j] = *(const float4*)&Bs[tx + 16 * j][k];
#pragma unroll
      for (int i = 0; i < 4; i++)
#pragma unroll
        for (int j = 0; j < 3; j++) {
          float s = acc[i][j];
          s = fmaf(a[i].x, b[j].x, s);
          s = fmaf(a[i].y, b[j].y, s);
          s = fmaf(a[i].z, b[j].z, s);
          s = fmaf(a[i].w, b[j].w, s);
          acc[i][j] = s;
        }
    }
#pragma unroll
    for (int i = 0; i < 4; i++)
#pragma unroll
      for (int j = 0; j < 3; j++) {
        int n = n0 + tx + 16 * j;
        float v = acc[i][j];
        if (n < 1024 && v > tv[i][2]) {
          if (v > tv[i][1]) {
            tv[i][2] = tv[i][1]; tc[i][2] = tc[i][1];
            if (v > tv[i][0]) {
              tv[i][1] = tv[i][0]; tc[i][1] = tc[i][0];
              tv[i][0] = v; tc[i][0] = n;
            } else { tv[i][1] = v; tc[i][1] = n; }
          } else { tv[i][2] = v; tc[i][2] = n; }
        }
      }
  }
  __syncthreads();
  // merge per-row candidates (16 tx-threads x 3) via LDS scratch overlaying Bs
  float* scr = &Bs[0][0];  // need 64*16*6 = 24576 floats? no: 6144 floats, Bs has 6336
#pragma unroll
  for (int i = 0; i < 4; i++) {
    int m = ty + 16 * i;
    float* p = scr + (m * 16 + tx) * 6;
    p[0] = tv[i][0]; p[1] = tv[i][1]; p[2] = tv[i][2];
    ((int*)p)[3] = tc[i][0]; ((int*)p)[4] = tc[i][1]; ((int*)p)[5] = tc[i][2];
  }
  __syncthreads();
  if (t < 64 && m0 + t < M) {
    int m = t;
    float v0 = -INFINITY, v1 = -INFINITY, v2 = -INFINITY;
    int c0 = 0, c1 = 0, c2 = 0;
    for (int x = 0; x < 16; x++) {
      const float* p = scr + (m * 16 + x) * 6;
#pragma unroll
      for (int k = 0; k < 3; k++) {
        float v = p[k];
        int c = ((const int*)p)[3 + k];
        if (v > v2) {
          if (v > v1) {
            v2 = v1; c2 = c1;
            if (v > v0) { v1 = v0; c1 = c0; v0 = v; c0 = c; }
            else { v1 = v; c1 = c; }
          } else { v2 = v; c2 = c; }
        }
      }
    }
    size_t base = (size_t)(m0 + m) * 3;
    idx3[base + 0] = c0; idx3[base + 1] = c1; idx3[base + 2] = c2;
  }
}

// ---------------- CSR build ----------------
__global__ void k_count(const int* __restrict__ idx3, int* __restrict__ cnt, int E) {
  int e = blockIdx.x * 256 + threadIdx.x;
  if (e < E) atomicAdd(&cnt[idx3[e]], 1);
}

__global__ __launch_bounds__(1024) void k_scan(const int* __restrict__ cnt,
                                               int* __restrict__ offs,
                                               int* __restrict__ cur) {
  __shared__ int s[1024];
  int t = threadIdx.x;
  int own = cnt[t];
  s[t] = own;
  __syncthreads();
  for (int o = 1; o < 1024; o <<= 1) {
    int v = (t >= o) ? s[t - o] : 0;
    __syncthreads();
    s[t] += v;
    __syncthreads();
  }
  int excl = s[t] - own;
  offs[t] = excl;
  cur[t] = excl;
  if (t == 1023) offs[1024] = s[1023];
}

__global__ void k_scatter(const int* __restrict__ idx3, int* __restrict__ cur,
                          int* __restrict__ edge_item, int E) {
  int e = blockIdx.x * 256 + threadIdx.x;
  if (e < E) {
    int c = idx3[e];
    int pos = atomicAdd(&cur[c], 1);
    edge_item[pos] = e / 3;
  }
}

// ---------------- per-intent segment softmax + weighted item sum ----------------
__global__ __launch_bounds__(256) void k_intent(const float* __restrict__ item_w,
                                                const float* __restrict__ intent_w,
                                                const float* __restrict__ la,
                                                const int* __restrict__ offs,
                                                const int* __restrict__ edge_item,
                                                float* __restrict__ intent_new) {
  int c = blockIdx.x;
  int start = offs[c], end = offs[c + 1];
  int lane = threadIdx.x & 63, w = threadIdx.x >> 6;
  float2 cw = ((const float2*)(intent_w + (size_t)c * 128))[lane];
  float2 lav = ((const float2*)la)[lane];
  float pmx = cw.x * lav.x, pmy = cw.y * lav.y;
  __shared__ float smx[4], sden[4], sacc[4][128];
  float mx = -INFINITY;
  for (int e = start + w; e < end; e += 4) {
    int i = edge_item[e];
    float2 iv = ((const float2*)(item_w + (size_t)i * 128))[lane];
    float d = iv.x * pmx + iv.y * pmy;
#pragma unroll
    for (int o = 32; o; o >>= 1) d += __shfl_xor(d, o, 64);
    float e1 = d >= 0.f ? d : 0.2f * d;
    mx = fmaxf(mx, e1);
  }
  if (lane == 0) smx[w] = mx;
  __syncthreads();
  mx = fmaxf(fmaxf(smx[0], smx[1]), fmaxf(smx[2], smx[3]));
  float ax = 0.f, ay = 0.f, den = 0.f;
  for (int e = start + w; e < end; e += 4) {
    int i = edge_item[e];
    float2 iv = ((const float2*)(item_w + (size_t)i * 128))[lane];
    float d = iv.x * pmx + iv.y * pmy;
#pragma unroll
    for (int o = 32; o; o >>= 1) d += __shfl_xor(d, o, 64);
    float e1 = d >= 0.f ? d : 0.2f * d;
    float ex = expf(e1 - mx);
    den += ex;
    ax = fmaf(ex, iv.x, ax);
    ay = fmaf(ex, iv.y, ay);
  }
  sacc[w][2 * lane] = ax;
  sacc[w][2 * lane + 1] = ay;
  if (lane == 0) sden[w] = den;
  __syncthreads();
  if (w == 0) {
    float dt = sden[0] + sden[1] + sden[2] + sden[3];
    float inv = dt > 0.f ? 1.f / dt : 0.f;
    float sx = sacc[0][2 * lane] + sacc[1][2 * lane] + sacc[2][2 * lane] + sacc[3][2 * lane];
    float sy = sacc[0][2 * lane + 1] + sacc[1][2 * lane + 1] + sacc[2][2 * lane + 1] +
               sacc[3][2 * lane + 1];
    intent_new[(size_t)c * 128 + 2 * lane] = sx * inv;
    intent_new[(size_t)c * 128 + 2 * lane + 1] = sy * inv;
  }
}

// ---------------- h_intent for the referenced (b,n) items ----------------
__global__ __launch_bounds__(256) void k_hintent(const int* __restrict__ items,
                                                 const float* __restrict__ item_w,
                                                 const int* __restrict__ idx3,
                                                 const float* __restrict__ intent_new,
                                                 const float* __restrict__ lb,
                                                 float* __restrict__ h_intent, int total) {
  int g = (blockIdx.x * 256 + threadIdx.x) >> 6;
  int lane = threadIdx.x & 63;
  if (g >= total) return;
  int it = items[g];
  float2 iw = ((const float2*)(item_w + (size_t)it * 128))[lane];
  float2 lbv = ((const float2*)lb)[lane];
  float e2[3];
  float2 nb[3];
#pragma unroll
  for (int k = 0; k < 3; k++) {
    int c = idx3[(size_t)it * 3 + k];
    nb[k] = ((const float2*)(intent_new + (size_t)c * 128))[lane];
    float d = iw.x * nb[k].x * lbv.x + iw.y * nb[k].y * lbv.y;
#pragma unroll
    for (int o = 32; o; o >>= 1) d += __shfl_xor(d, o, 64);
    e2[k] = d >= 0.f ? d : 0.2f * d;
  }
  float m = fmaxf(fmaxf(e2[0], e2[1]), e2[2]);
  float x0 = expf(e2[0] - m), x1 = expf(e2[1] - m), x2 = expf(e2[2] - m);
  float inv = 1.f / (x0 + x1 + x2);
  float nx = (x0 * nb[0].x + x1 * nb[1].x + x2 * nb[2].x) * inv;
  float ny = (x0 * nb[0].y + x1 * nb[1].y + x2 * nb[2].y) * inv;
  ((float2*)(h_intent + (size_t)g * 128))[lane] =
      make_float2(0.5f * iw.x + 0.5f * nx, 0.5f * iw.y + 0.5f * ny);
}

// ---------------- fused per-session local graph + readout -> hf ----------------
__global__ __launch_bounds__(256) void k_session(
    const int* __restrict__ items, const int* __restrict__ Aadj,
    const int* __restrict__ inputs, const int* __restrict__ masks,
    const int* __restrict__ alias_inp, const float* __restrict__ item_w,
    const float* __restrict__ pos_emb, const float* __restrict__ la1,
    const float* __restrict__ la2, const float* __restrict__ lb1,
    const float* __restrict__ lb2, const float* __restrict__ W1,
    const float* __restrict__ b1, const float* __restrict__ W2,
    const float* __restrict__ b2, const float* __restrict__ w3,
    const float* __restrict__ h_intent, float* __restrict__ hf_out) {
  const int b = blockIdx.x;
  const int t = threadIdx.x;
  const int lane = t & 63, w = t >> 6;
  __shared__ float hi[50][128];    // item rows -> later sessions
  __shared__ float outb[50][128];  // output rows -> later hir
  __shared__ float att[50][50];
  __shared__ float hsb[128], hsrb[128], q2b[128];
  __shared__ float cj1[50], cj2[50], alb[50];
  __shared__ float tmp2[2][128];
  __shared__ float wred[4][32];

  float mfs = 0.f;
  for (int l = 0; l < 50; l++) mfs += (float)masks[b * 50 + l];

  // gather hi + hs partials
  for (int i = t; i < 50 * 32; i += 256) {
    int r = i >> 5, c4 = (i & 31) << 2;
    int it = items[b * 50 + r];
    *(float4*)&hi[r][c4] = *(const float4*)(item_w + (size_t)it * 128 + c4);
  }
  {
    int d = t & 127, lh = t >> 7;
    float acc = 0.f;
    for (int l = lh; l < 50; l += 2) {
      float m = (float)masks[b * 50 + l];
      int row = inputs[b * 50 + l];
      acc += m * item_w[(size_t)row * 128 + d];
    }
    tmp2[lh][d] = acc;
  }
  __syncthreads();
  if (t < 128) hsb[t] = (tmp2[0][t] + tmp2[1][t]) / mfs;
  __syncthreads();
  // cj1/cj2
  {
    float2 lb1v = ((const float2*)lb1)[lane];
    float2 lb2v = ((const float2*)lb2)[lane];
    float2 hs2 = *(const float2*)&hsb[2 * lane];
    for (int j = w; j < 50; j += 4) {
      float2 xj = *(const float2*)&hi[j][2 * lane];
      float s1 = hs2.x * xj.x * lb1v.x + hs2.y * xj.y * lb1v.y;
      float s2 = hs2.x * xj.x * lb2v.x + hs2.y * xj.y * lb2v.y;
#pragma unroll
      for (int o = 32; o; o >>= 1) {
        s1 += __shfl_xor(s1, o, 64);
        s2 += __shfl_xor(s2, o, 64);
      }
      if (lane == 0) { cj1[j] = s1; cj2[j] = s2; }
    }
  }
  __syncthreads();
  // att raw (A-selected, lrelu applied)
  {
    float2 la1v = ((const float2*)la1)[lane];
    float2 la2v = ((const float2*)la2)[lane];
    for (int i = w; i < 50; i += 4) {
      float2 xi = *(const float2*)&hi[i][2 * lane];
      float px1 = xi.x * la1v.x, py1 = xi.y * la1v.y;
      float px2 = xi.x * la2v.x, py2 = xi.y * la2v.y;
      for (int j = 0; j < 50; j++) {
        float2 xj = *(const float2*)&hi[j][2 * lane];
        float s1 = px1 * xj.x + py1 * xj.y;
        float s2 = px2 * xj.x + py2 * xj.y;
#pragma unroll
        for (int o = 32; o; o >>= 1) {
          s1 += __shfl_xor(s1, o, 64);
          s2 += __shfl_xor(s2, o, 64);
        }
        if (lane == 0) {
          int a = Aadj[((size_t)b * 50 + i) * 50 + j];
          float v;
          if (a == 1) { float x = s1 + cj1[j]; v = x >= 0.f ? x : 0.2f * x; }
          else if (a == 2) { float x = s2 + cj2[j]; v = x >= 0.f ? x : 0.2f * x; }
          else v = -9e15f;
          att[i][j] = v;
        }
      }
    }
  }
  __syncthreads();
  // row softmax
  for (int i = w; i < 50; i += 4) {
    float v = lane < 50 ? att[i][lane] : -INFINITY;
    float mx = v;
#pragma unroll
    for (int o = 32; o; o >>= 1) mx = fmaxf(mx, __shfl_xor(mx, o, 64));
    float ex = lane < 50 ? expf(v - mx) : 0.f;
    float sm = ex;
#pragma unroll
    for (int o = 32; o; o >>= 1) sm += __shfl_xor(sm, o, 64);
    if (lane < 50) att[i][lane] = ex / sm;
  }
  __syncthreads();
  // h_local + output
  for (int i = w; i < 50; i += 4) {
    float ax = 0.f, ay = 0.f;
    for (int j = 0; j < 50; j++) {
      float a = att[i][j];
      float2 xj = *(const float2*)&hi[j][2 * lane];
      ax = fmaf(a, xj.x, ax);
      ay = fmaf(a, xj.y, ay);
    }
    float2 hv = ((const float2*)(h_intent + ((size_t)b * 50 + i) * 128))[lane];
    *(float2*)&outb[i][2 * lane] =
        make_float2(ax + hv.x + ax * hv.x, ay + hv.y + ay * hv.y);
  }
  __syncthreads();
  // sessions gather into hi
  for (int i = t; i < 50 * 64; i += 256) {
    int r = i >> 6, c2 = (i & 63) << 1;
    int a = alias_inp[b * 50 + r];
    *(float2*)&hi[r][c2] = *(const float2*)&outb[a][c2];
  }
  __syncthreads();
  // hir into outb
  for (int i = t; i < 50 * 64; i += 256) {
    int r = i >> 6, c2 = (i & 63) << 1;
    float2 s = *(const float2*)&hi[r][c2];
    float2 p = *(const float2*)(pos_emb + (size_t)r * 128 + c2);
    *(float2*)&outb[r][c2] = make_float2(s.x + p.x, s.y + p.y);
  }
  __syncthreads();
  // hsr
  {
    int d = t & 127, lh = t >> 7;
    float acc = 0.f;
    for (int l = lh; l < 50; l += 2) acc += (float)masks[b * 50 + l] * outb[l][d];
    tmp2[lh][d] = acc;
  }
  __syncthreads();
  if (t < 128) hsrb[t] = (tmp2[0][t] + tmp2[1][t]) / mfs;
  __syncthreads();
  // q2 = hsr @ W2 + b2
  {
    int d = t & 127, kh = t >> 7;
    float acc = 0.f;
    for (int k = kh * 64; k < kh * 64 + 64; k++)
      acc = fmaf(hsrb[k], W2[(size_t)k * 128 + d], acc);
    tmp2[kh][d] = acc;
  }
  __syncthreads();
  if (t < 128) q2b[t] = b2[t] + tmp2[0][t] + tmp2[1][t];
  __syncthreads();
  // q1 rows + al
  {
    int d = t & 127, lh = t >> 7;
    float accq[25];
#pragma unroll
    for (int jj = 0; jj < 25; jj++) accq[jj] = b1[d];
    for (int k = 0; k < 128; k += 2) {
      float w1a = W1[(size_t)k * 128 + d];
      float w1b = W1[(size_t)(k + 1) * 128 + d];
#pragma unroll
      for (int jj = 0; jj < 25; jj++) {
        int l = lh + 2 * jj;
        float2 hv = *(const float2*)&outb[l][k];
        accq[jj] = fmaf(hv.x, w1a, accq[jj]);
        accq[jj] = fmaf(hv.y, w1b, accq[jj]);
      }
    }
    float w3v = w3[d], q2v = q2b[d];
#pragma unroll
    for (int jj = 0; jj < 25; jj++) {
      float s = 1.f / (1.f + expf(-(accq[jj] + q2v))) * w3v;
#pragma unroll
      for (int o = 32; o; o >>= 1) s += __shfl_xor(s, o, 64);
      if (lane == 0) wred[w][jj] = s;
    }
  }
  __syncthreads();
  if (t < 50) {
    int l = t, jj = l >> 1;
    alb[l] = (l & 1) ? (wred[2][jj] + wred[3][jj]) : (wred[0][jj] + wred[1][jj]);
  }
  __syncthreads();
  // hf
  if (t < 128) {
    int d = t;
    float acc = 0.f, pacc = 0.f;
    for (int l = 0; l < 50; l++) {
      float m = (float)masks[b * 50 + l];
      acc += alb[l] * hi[l][d] * m;
      pacc += pos_emb[(size_t)l * 128 + d] * m;
    }
    hf_out[(size_t)b * 128 + d] = acc + pos_emb[50 * 128 + d] * (pacc / mfs);
  }
}

// ---------------- scores = hf @ item_w[1:]^T ----------------
__global__ __launch_bounds__(256) void k_scores(const float* __restrict__ hfm,
                                                const float* __restrict__ Bw,
                                                float* __restrict__ C, int N) {
  __shared__ float As[64][GS];
  __shared__ float Bs[48][GS];
  const int t = threadIdx.x;
  const int n0 = blockIdx.x * 48;
  for (int i = t; i < 48 * 32; i += 256) {
    int r = i >> 5, c4 = (i & 31) << 2;
    float4 v = make_float4(0.f, 0.f, 0.f, 0.f);
    if (n0 + r < N) v = *(const float4*)(Bw + (size_t)(n0 + r) * 128 + c4);
    *(float4*)&Bs[r][c4] = v;
  }
  const int ty = t >> 4, tx = t & 15;
  for (int mt = 0; mt < 8; mt++) {
    __syncthreads();
    for (int i = t; i < 64 * 32; i += 256) {
      int r = i >> 5, c4 = (i & 31) << 2;
      *(float4*)&As[r][c4] = *(const float4*)(hfm + (size_t)(mt * 64 + r) * 128 + c4);
    }
    __syncthreads();
    float acc[4][3];
#pragma unroll
    for (int i = 0; i < 4; i++)
#pragma unroll
      for (int j = 0; j < 3; j++) acc[i][j] = 0.f;
#pragma unroll 4
    for (int k = 0; k < 128; k += 4) {
      float4 a[4], b[3];
#pragma unroll
      for (int i = 0; i < 4; i++) a[i] = *(const float4*)&As[ty + 16 * i][k];
#pragma unroll
      for (int j = 0; j < 3; j++) b[j] = *(const float4*)&Bs[tx + 16 * j][k];
#pragma unroll
      for (int i = 0; i < 4; i++)
#pragma unroll
        for (int j = 0; j < 3; j++) {
          float s = acc[i][j];
          s = fmaf(a[i].x, b[j].x, s);
          s = fmaf(a[i].y, b[j].y, s);
          s = fmaf(a[i].z, b[j].z, s);
          s = fmaf(a[i].w, b[j].w, s);
          acc[i][j] = s;
        }
    }
#pragma unroll
    for (int i = 0; i < 4; i++) {
      int m = mt * 64 + ty + 16 * i;
#pragma unroll
      for (int j = 0; j < 3; j++) {
        int n = n0 + tx + 16 * j;
        if (n < N) C[(size_t)m * N + n] = acc[i][j];
      }
    }
  }
}

extern "C" void kernel_launch(void* const* d_in, const int* in_sizes, int n_in,
                              void* d_out, int out_size, void* d_ws, size_t ws_size,
                              hipStream_t stream) {
  const int* items = (const int*)d_in[0];
  const int* Aadj = (const int*)d_in[1];
  const int* inputs = (const int*)d_in[2];
  const int* masks = (const int*)d_in[3];
  const int* alias = (const int*)d_in[4];
  const float* item_emb = (const float*)d_in[5];
  const float* intent_emb = (const float*)d_in[6];
  const float* pos_emb = (const float*)d_in[7];
  const float* lq = (const float*)d_in[8];
  const float* lk = (const float*)d_in[9];
  const float* la = (const float*)d_in[10];
  const float* lb = (const float*)d_in[11];
  const float* la1 = (const float*)d_in[12];
  const float* la2 = (const float*)d_in[13];
  const float* lb1 = (const float*)d_in[14];
  const float* lb2 = (const float*)d_in[15];
  const float* W1 = (const float*)d_in[16];
  const float* b1 = (const float*)d_in[17];
  const float* W2 = (const float*)d_in[18];
  const float* b2 = (const float*)d_in[19];
  const float* w3 = (const float*)d_in[20];
  float* out = (float*)d_out;

  char* p = (char*)d_ws;
  auto alloc = [&](size_t bytes) {
    char* r = p;
    p += (bytes + 511) & ~(size_t)511;
    return r;
  };
  float* item_w = (float*)alloc(100000ull * 128 * 4);
  float* P = (float*)alloc(100000ull * 128 * 4);
  float* intw = (float*)alloc(1024ull * 128 * 4);
  float* CK = (float*)alloc(1024ull * 128 * 4);
  float* intent_new = (float*)alloc(1024ull * 128 * 4);
  float* lqT = (float*)alloc(128 * 128 * 4);
  float* lkT = (float*)alloc(128 * 128 * 4);
  int* idx3 = (int*)alloc(300000ull * 4);
  int* cnt = (int*)alloc(1024 * 4);
  int* offs = (int*)alloc(1025 * 4);
  int* cur = (int*)alloc(1024 * 4);
  int* edge_item = (int*)alloc(300000ull * 4);
  float* hf = (float*)alloc(512 * 128 * 4);
  float* h_int = P;  // reuse: P dead after k_sim_top3

  k_norm<<<25000, 256, 0, stream>>>(item_emb, item_w, 100000);
  k_norm<<<256, 256, 0, stream>>>(intent_emb, intw, 1024);
  k_t128<<<1, 256, 0, stream>>>(lq, lqT);
  k_t128<<<1, 256, 0, stream>>>(lk, lkT);
  k_gemm_abt<<<dim3(3, 16), 256, 0, stream>>>(intw, lkT, CK, 1024, 128);
  k_gemm_abt<<<dim3(3, 1563), 256, 0, stream>>>(item_w, lqT, P, 100000, 128);
  k_sim_top3<<<1563, 256, 0, stream>>>(P, CK, idx3, 100000);
  hipMemsetAsync(cnt, 0, 1024 * 4, stream);
  k_count<<<(300000 + 255) / 256, 256, 0, stream>>>(idx3, cnt, 300000);
  k_scan<<<1, 1024, 0, stream>>>(cnt, offs, cur);
  k_scatter<<<(300000 + 255) / 256, 256, 0, stream>>>(idx3, cur, edge_item, 300000);
  k_intent<<<1024, 256, 0, stream>>>(item_w, intw, la, offs, edge_item, intent_new);
  k_hintent<<<6400, 256, 0, stream>>>(items, item_w, idx3, intent_new, lb, h_int, 25600);
  k_session<<<512, 256, 0, stream>>>(items, Aadj, inputs, masks, alias, item_w, pos_emb,
                                     la1, la2, lb1, lb2, W1, b1, W2, b2, w3, h_int, hf);
  k_scores<<<2084, 256, 0, stream>>>(hf, item_w + 128, out, 99999);
}

// Round 2
// 1752.923 us; speedup vs baseline: 1.4662x; 1.4662x over previous
//
#include <hip/hip_runtime.h>
#include <math.h>

typedef __attribute__((ext_vector_type(4))) float f32x4;
typedef __attribute__((ext_vector_type(8))) short bf16x8;

static __device__ __forceinline__ unsigned short f2bf(float f) {
  unsigned int u = __float_as_uint(f);
  unsigned int r = (u + 0x7FFFu + ((u >> 16) & 1u)) >> 16;
  return (unsigned short)r;
}
static __device__ __forceinline__ float bf2f(unsigned short h) {
  return __uint_as_float(((unsigned int)h) << 16);
}

#define INS3(vv, cc) do { float _v=(vv); int _c=(cc); \
  if (_v > v2) { if (_v > v1) { v2=v1; c2=c1i; if (_v > v0) { v1=v0; c1i=c0; v0=_v; c0=_c; } \
  else { v1=_v; c1i=_c; } } else { v2=_v; c2=_c; } } } while(0)

#define INS4(vv, cc) do { float _v=(vv); int _c=(cc); \
  if (_v > w3v) { if (_v > w1v) { if (_v > w0v) { w3v=w2v;d3=d2; w2v=w1v;d2=d1; w1v=w0v;d1=d0; w0v=_v;d0=_c; } \
    else { w3v=w2v;d3=d2; w2v=w1v;d2=d1; w1v=_v;d1=_c; } } \
    else { if (_v > w2v) { w3v=w2v;d3=d2; w2v=_v;d2=_c; } else { w3v=_v; d3=_c; } } } } while(0)

// ---------------- row L2-normalize (for intents) ----------------
__global__ __launch_bounds__(256) void k_norm(const float* __restrict__ in,
                                              float* __restrict__ out, int R) {
  int g = (blockIdx.x * 256 + threadIdx.x) >> 6;
  int lane = threadIdx.x & 63;
  if (g >= R) return;
  float2 v = ((const float2*)(in + (size_t)g * 128))[lane];
  float ss = v.x * v.x + v.y * v.y;
#pragma unroll
  for (int o = 32; o; o >>= 1) ss += __shfl_xor(ss, o, 64);
  float s = 1.0f / sqrtf(ss);
  ((float2*)(out + (size_t)g * 128))[lane] = make_float2(v.x * s, v.y * s);
}

// ---------------- items: normalize + write fp32 + split [hi|hi|lo] ----------------
__global__ __launch_bounds__(256) void k_prep_item(const float* __restrict__ in,
                                                   float* __restrict__ item_w,
                                                   unsigned short* __restrict__ itp, int R) {
  int g = (blockIdx.x * 256 + threadIdx.x) >> 6;
  int lane = threadIdx.x & 63;
  if (g >= R) return;
  float2 v = ((const float2*)(in + (size_t)g * 128))[lane];
  float ss = v.x * v.x + v.y * v.y;
#pragma unroll
  for (int o = 32; o; o >>= 1) ss += __shfl_xor(ss, o, 64);
  float s = 1.0f / sqrtf(ss);
  float x = v.x * s, y = v.y * s;
  ((float2*)(item_w + (size_t)g * 128))[lane] = make_float2(x, y);
  unsigned short hx = f2bf(x), hy = f2bf(y);
  unsigned short lx = f2bf(x - bf2f(hx)), ly = f2bf(y - bf2f(hy));
  unsigned short* row = itp + (size_t)g * 384;
  ((ushort2*)row)[lane] = make_ushort2(hx, hy);
  ((ushort2*)(row + 128))[lane] = make_ushort2(hx, hy);
  ((ushort2*)(row + 256))[lane] = make_ushort2(lx, ly);
}

// ---------------- generic split [hi|lo|hi] ----------------
__global__ __launch_bounds__(256) void k_split(const float* __restrict__ in,
                                               unsigned short* __restrict__ outp, int R) {
  int g = (blockIdx.x * 256 + threadIdx.x) >> 6;
  int lane = threadIdx.x & 63;
  if (g >= R) return;
  float2 v = ((const float2*)(in + (size_t)g * 128))[lane];
  unsigned short hx = f2bf(v.x), hy = f2bf(v.y);
  unsigned short lx = f2bf(v.x - bf2f(hx)), ly = f2bf(v.y - bf2f(hy));
  unsigned short* row = outp + (size_t)g * 384;
  ((ushort2*)row)[lane] = make_ushort2(hx, hy);
  ((ushort2*)(row + 128))[lane] = make_ushort2(lx, ly);
  ((ushort2*)(row + 256))[lane] = make_ushort2(hx, hy);
}

// ---------------- 128x128 transpose ----------------
__global__ __launch_bounds__(256) void k_t128(const float* __restrict__ in,
                                              float* __restrict__ out) {
  for (int i = threadIdx.x; i < 128 * 128; i += 256) {
    int k = i >> 7, j = i & 127;
    out[j * 128 + k] = in[i];
  }
}

// ---------------- small fp32 C[MxN] = A[Mx128] @ B[Nx128]^T ----------------
__global__ __launch_bounds__(256) void k_gemm_abt(const float* __restrict__ A,
                                                  const float* __restrict__ B,
                                                  float* __restrict__ C, int M, int N) {
  __shared__ float As[64][132];
  __shared__ float Bs[48][132];
  const int t = threadIdx.x;
  const int m0 = blockIdx.y * 64, n0 = blockIdx.x * 48;
  for (int i = t; i < 64 * 32; i += 256) {
    int r = i >> 5, c4 = (i & 31) << 2;
    float4 v = make_float4(0.f, 0.f, 0.f, 0.f);
    if (m0 + r < M) v = *(const float4*)(A + (size_t)(m0 + r) * 128 + c4);
    *(float4*)&As[r][c4] = v;
  }
  for (int i = t; i < 48 * 32; i += 256) {
    int r = i >> 5, c4 = (i & 31) << 2;
    float4 v = make_float4(0.f, 0.f, 0.f, 0.f);
    if (n0 + r < N) v = *(const float4*)(B + (size_t)(n0 + r) * 128 + c4);
    *(float4*)&Bs[r][c4] = v;
  }
  __syncthreads();
  const int ty = t >> 4, tx = t & 15;
  float acc[4][3];
#pragma unroll
  for (int i = 0; i < 4; i++)
#pragma unroll
    for (int j = 0; j < 3; j++) acc[i][j] = 0.f;
#pragma unroll 4
  for (int k = 0; k < 128; k += 4) {
    float4 a[4], b[3];
#pragma unroll
    for (int i = 0; i < 4; i++) a[i] = *(const float4*)&As[ty + 16 * i][k];
#pragma unroll
    for (int j = 0; j < 3; j++) b[j] = *(const float4*)&Bs[tx + 16 * j][k];
#pragma unroll
    for (int i = 0; i < 4; i++)
#pragma unroll
      for (int j = 0; j < 3; j++) {
        float s = acc[i][j];
        s = fmaf(a[i].x, b[j].x, s);
        s = fmaf(a[i].y, b[j].y, s);
        s = fmaf(a[i].z, b[j].z, s);
        s = fmaf(a[i].w, b[j].w, s);
        acc[i][j] = s;
      }
  }
#pragma unroll
  for (int i = 0; i < 4; i++) {
    int m = m0 + ty + 16 * i;
    if (m >= M) continue;
#pragma unroll
    for (int j = 0; j < 3; j++) {
      int n = n0 + tx + 16 * j;
      if (n < N) C[(size_t)m * N + n] = acc[i][j];
    }
  }
}

// ---------------- MFMA split-bf16 GEMM: C[M x N] = A[M x 384] @ B[N x 384]^T ----------------
// MODE 0: sim — keep per-128-col-chunk top-4 candidate columns -> pi4[row][chunk][4]
// MODE 1: scores — store C with col guard n < Nc
template <int MODE>
__global__ __launch_bounds__(256, 2) void k_mfma(const unsigned short* __restrict__ Abase,
                                                 const unsigned short* __restrict__ Bbase,
                                                 float* __restrict__ C, int ldc, int Nc,
                                                 int* __restrict__ pi4, int Mv) {
  __shared__ __align__(16) char lds[32768];  // main loop uses 20480; epilogue reuses 32K
  const int t = threadIdx.x, l = t & 63, w = t >> 6;
  const int wr = w >> 1, wc = w & 1;

  int m0, n0, chunk = 0;
  {
    int g = blockIdx.x;
    int xcd = g & 7, r = g >> 3;
    if (MODE == 0) {
      chunk = r & 7;
      int mt = (r >> 3) * 8 + xcd;
      if (mt >= ((Mv + 127) >> 7)) return;
      m0 = mt << 7;
      n0 = chunk << 7;
    } else {
      int mq = r & 3;
      int nt = (r >> 2) * 8 + xcd;
      if (nt >= ((Nc + 127) >> 7)) return;
      m0 = mq << 7;
      n0 = nt << 7;
    }
  }
  const unsigned short* A = Abase + (size_t)m0 * 384;
  const unsigned short* B = Bbase + (size_t)n0 * 384;

  const int r1 = t >> 2, c1 = t & 3;  // staging slot: row r1 (and r1+64), 16B col c1
  f32x4 acc[4][4];
  {
    f32x4 z = {0.f, 0.f, 0.f, 0.f};
#pragma unroll
    for (int i = 0; i < 4; i++)
#pragma unroll
      for (int j = 0; j < 4; j++) acc[i][j] = z;
  }

  int4 sa0, sa1, sb0, sb1;
  {
    const unsigned short* ka = A;
    const unsigned short* kb = B;
    sa0 = *(const int4*)(ka + (size_t)r1 * 384 + c1 * 8);
    sa1 = *(const int4*)(ka + (size_t)(r1 + 64) * 384 + c1 * 8);
    sb0 = *(const int4*)(kb + (size_t)r1 * 384 + c1 * 8);
    sb1 = *(const int4*)(kb + (size_t)(r1 + 64) * 384 + c1 * 8);
  }

  for (int kt = 0; kt < 12; ++kt) {
    if (kt) __syncthreads();  // readers of lds done
    // write current tile regs -> LDS (80B padded rows)
    *(int4*)(lds + r1 * 80 + c1 * 16) = sa0;
    *(int4*)(lds + (r1 + 64) * 80 + c1 * 16) = sa1;
    *(int4*)(lds + 10240 + r1 * 80 + c1 * 16) = sb0;
    *(int4*)(lds + 10240 + (r1 + 64) * 80 + c1 * 16) = sb1;
    __syncthreads();  // LDS tile visible
    if (kt < 11) {    // issue next-tile global loads; overlap with MFMA below
      const unsigned short* ka = A + (kt + 1) * 32;
      const unsigned short* kb = B + (kt + 1) * 32;
      sa0 = *(const int4*)(ka + (size_t)r1 * 384 + c1 * 8);
      sa1 = *(const int4*)(ka + (size_t)(r1 + 64) * 384 + c1 * 8);
      sb0 = *(const int4*)(kb + (size_t)r1 * 384 + c1 * 8);
      sb1 = *(const int4*)(kb + (size_t)(r1 + 64) * 384 + c1 * 8);
    }
    bf16x8 af[4], bfr[4];
#pragma unroll
    for (int i = 0; i < 4; i++) {
      int ar = wr * 64 + i * 16 + (l & 15);
      af[i] = *(const bf16x8*)(lds + ar * 80 + (l >> 4) * 16);
      int br = wc * 64 + i * 16 + (l & 15);
      bfr[i] = *(const bf16x8*)(lds + 10240 + br * 80 + (l >> 4) * 16);
    }
#pragma unroll
    for (int i = 0; i < 4; i++)
#pragma unroll
      for (int j = 0; j < 4; j++)
        acc[i][j] = __builtin_amdgcn_mfma_f32_16x16x32_bf16(af[i], bfr[j], acc[i][j], 0, 0, 0);
  }

  if (MODE == 1) {
#pragma unroll
    for (int i = 0; i < 4; i++)
#pragma unroll
      for (int q = 0; q < 4; q++) {
        int m = m0 + wr * 64 + i * 16 + (l >> 4) * 4 + q;
#pragma unroll
        for (int j = 0; j < 4; j++) {
          int n = n0 + wc * 64 + j * 16 + (l & 15);
          if (n < Nc) C[(size_t)m * ldc + n] = acc[i][j][q];
        }
      }
  } else {
    // per-lane top-2 over its 4 cols (j embedded in value LSBs), LDS merge -> chunk top-4 cols
    __syncthreads();
    float* sp = (float*)lds;  // [128 rows][32 contrib][2]
#pragma unroll
    for (int i = 0; i < 4; i++)
#pragma unroll
      for (int q = 0; q < 4; q++) {
        float va = -3.0e38f, vb = -3.0e38f;
        int ja = 0, jb = 0;
#pragma unroll
        for (int j = 0; j < 4; j++) {
          float v = acc[i][j][q];
          if (v > vb) {
            if (v > va) { vb = va; jb = ja; va = v; ja = j; }
            else { vb = v; jb = j; }
          }
        }
        int row = wr * 64 + i * 16 + (l >> 4) * 4 + q;
        int contrib = wc * 16 + (l & 15);
        sp[(row * 32 + contrib) * 2] =
            __uint_as_float((__float_as_uint(va) & ~3u) | (unsigned)ja);
        sp[(row * 32 + contrib) * 2 + 1] =
            __uint_as_float((__float_as_uint(vb) & ~3u) | (unsigned)jb);
      }
    __syncthreads();
    if (t < 128) {
      int grow = m0 + t;
      if (grow < Mv) {
        float w0v = -3.0e38f, w1v = -3.0e38f, w2v = -3.0e38f, w3v = -3.0e38f;
        int d0 = 0, d1 = 0, d2 = 0, d3 = 0;
        for (int cbt = 0; cbt < 64; cbt++) {
          float v = sp[t * 64 + cbt];
          int contrib = cbt >> 1;
          int j = (int)(__float_as_uint(v) & 3u);
          int col = n0 + (contrib >> 4) * 64 + j * 16 + (contrib & 15);
          INS4(v, col);
        }
        size_t pb = (size_t)grow * 32 + chunk * 4;
        pi4[pb] = d0; pi4[pb + 1] = d1; pi4[pb + 2] = d2; pi4[pb + 3] = d3;
      }
    }
  }
}

// ---------------- exact fp32 rescore of 32 candidates -> top-3 intents ----------------
__global__ __launch_bounds__(256) void k_rescore(const int* __restrict__ pi4,
                                                 const float* __restrict__ item_w,
                                                 const float* __restrict__ Gt,
                                                 int* __restrict__ idx3, int M) {
  int r = (blockIdx.x * 256 + threadIdx.x) >> 6;
  int l = threadIdx.x & 63;
  if (r >= M) return;
  float2 iw = ((const float2*)(item_w + (size_t)r * 128))[l];
  float v0 = -3.0e38f, v1 = -3.0e38f, v2 = -3.0e38f;
  int c0 = 0, c1i = 0, c2 = 0;
  for (int s = 0; s < 32; s++) {
    int c = pi4[(size_t)r * 32 + s];
    float2 g = ((const float2*)(Gt + (size_t)c * 128))[l];
    float d = iw.x * g.x + iw.y * g.y;
#pragma unroll
    for (int o = 32; o; o >>= 1) d += __shfl_xor(d, o, 64);
    INS3(d, c);
  }
  if (l == 0) {
    idx3[r * 3] = c0; idx3[r * 3 + 1] = c1i; idx3[r * 3 + 2] = c2;
  }
}

// ---------------- CSR build ----------------
__global__ void k_count(const int* __restrict__ idx3, int* __restrict__ cnt, int E) {
  int e = blockIdx.x * 256 + threadIdx.x;
  if (e < E) atomicAdd(&cnt[idx3[e]], 1);
}

__global__ __launch_bounds__(1024) void k_scan(const int* __restrict__ cnt,
                                               int* __restrict__ offs,
                                               int* __restrict__ cur) {
  __shared__ int s[1024];
  int t = threadIdx.x;
  int own = cnt[t];
  s[t] = own;
  __syncthreads();
  for (int o = 1; o < 1024; o <<= 1) {
    int v = (t >= o) ? s[t - o] : 0;
    __syncthreads();
    s[t] += v;
    __syncthreads();
  }
  int excl = s[t] - own;
  offs[t] = excl;
  cur[t] = excl;
  if (t == 1023) offs[1024] = s[1023];
}

__global__ void k_scatter(const int* __restrict__ idx3, int* __restrict__ cur,
                          int* __restrict__ edge_item, int E) {
  int e = blockIdx.x * 256 + threadIdx.x;
  if (e < E) {
    int c = idx3[e];
    int pos = atomicAdd(&cur[c], 1);
    edge_item[pos] = e / 3;
  }
}

// ---------------- per-intent segment softmax + weighted item sum ----------------
__global__ __launch_bounds__(256) void k_intent(const float* __restrict__ item_w,
                                                const float* __restrict__ intent_w,
                                                const float* __restrict__ la,
                                                const int* __restrict__ offs,
                                                const int* __restrict__ edge_item,
                                                float* __restrict__ intent_new) {
  int c = blockIdx.x;
  int start = offs[c], end = offs[c + 1];
  int lane = threadIdx.x & 63, w = threadIdx.x >> 6;
  float2 cw = ((const float2*)(intent_w + (size_t)c * 128))[lane];
  float2 lav = ((const float2*)la)[lane];
  float pmx = cw.x * lav.x, pmy = cw.y * lav.y;
  __shared__ float smx[4], sden[4], sacc[4][128];
  float mx = -INFINITY;
  for (int e = start + w; e < end; e += 4) {
    int i = edge_item[e];
    float2 iv = ((const float2*)(item_w + (size_t)i * 128))[lane];
    float d = iv.x * pmx + iv.y * pmy;
#pragma unroll
    for (int o = 32; o; o >>= 1) d += __shfl_xor(d, o, 64);
    float e1 = d >= 0.f ? d : 0.2f * d;
    mx = fmaxf(mx, e1);
  }
  if (lane == 0) smx[w] = mx;
  __syncthreads();
  mx = fmaxf(fmaxf(smx[0], smx[1]), fmaxf(smx[2], smx[3]));
  float ax = 0.f, ay = 0.f, den = 0.f;
  for (int e = start + w; e < end; e += 4) {
    int i = edge_item[e];
    float2 iv = ((const float2*)(item_w + (size_t)i * 128))[lane];
    float d = iv.x * pmx + iv.y * pmy;
#pragma unroll
    for (int o = 32; o; o >>= 1) d += __shfl_xor(d, o, 64);
    float e1 = d >= 0.f ? d : 0.2f * d;
    float ex = expf(e1 - mx);
    den += ex;
    ax = fmaf(ex, iv.x, ax);
    ay = fmaf(ex, iv.y, ay);
  }
  sacc[w][2 * lane] = ax;
  sacc[w][2 * lane + 1] = ay;
  if (lane == 0) sden[w] = den;
  __syncthreads();
  if (w == 0) {
    float dt = sden[0] + sden[1] + sden[2] + sden[3];
    float inv = dt > 0.f ? 1.f / dt : 0.f;
    float sx = sacc[0][2 * lane] + sacc[1][2 * lane] + sacc[2][2 * lane] + sacc[3][2 * lane];
    float sy = sacc[0][2 * lane + 1] + sacc[1][2 * lane + 1] + sacc[2][2 * lane + 1] +
               sacc[3][2 * lane + 1];
    intent_new[(size_t)c * 128 + 2 * lane] = sx * inv;
    intent_new[(size_t)c * 128 + 2 * lane + 1] = sy * inv;
  }
}

// ---------------- h_intent for the referenced (b,n) items ----------------
__global__ __launch_bounds__(256) void k_hintent(const int* __restrict__ items,
                                                 const float* __restrict__ item_w,
                                                 const int* __restrict__ idx3,
                                                 const float* __restrict__ intent_new,
                                                 const float* __restrict__ lb,
                                                 float* __restrict__ h_intent, int total) {
  int g = (blockIdx.x * 256 + threadIdx.x) >> 6;
  int lane = threadIdx.x & 63;
  if (g >= total) return;
  int it = items[g];
  float2 iw = ((const float2*)(item_w + (size_t)it * 128))[lane];
  float2 lbv = ((const float2*)lb)[lane];
  float e2[3];
  float2 nb[3];
#pragma unroll
  for (int k = 0; k < 3; k++) {
    int c = idx3[(size_t)it * 3 + k];
    nb[k] = ((const float2*)(intent_new + (size_t)c * 128))[lane];
    float d = iw.x * nb[k].x * lbv.x + iw.y * nb[k].y * lbv.y;
#pragma unroll
    for (int o = 32; o; o >>= 1) d += __shfl_xor(d, o, 64);
    e2[k] = d >= 0.f ? d : 0.2f * d;
  }
  float m = fmaxf(fmaxf(e2[0], e2[1]), e2[2]);
  float x0 = expf(e2[0] - m), x1 = expf(e2[1] - m), x2 = expf(e2[2] - m);
  float inv = 1.f / (x0 + x1 + x2);
  float nx = (x0 * nb[0].x + x1 * nb[1].x + x2 * nb[2].x) * inv;
  float ny = (x0 * nb[0].y + x1 * nb[1].y + x2 * nb[2].y) * inv;
  ((float2*)(h_intent + (size_t)g * 128))[lane] =
      make_float2(0.5f * iw.x + 0.5f * nx, 0.5f * iw.y + 0.5f * ny);
}

// ---------------- fused per-session local graph + readout -> hf ----------------
__global__ __launch_bounds__(256) void k_session(
    const int* __restrict__ items, const int* __restrict__ Aadj,
    const int* __restrict__ inputs, const int* __restrict__ masks,
    const int* __restrict__ alias_inp, const float* __restrict__ item_w,
    const float* __restrict__ pos_emb, const float* __restrict__ la1,
    const float* __restrict__ la2, const float* __restrict__ lb1,
    const float* __restrict__ lb2, const float* __restrict__ W1,
    const float* __restrict__ b1, const float* __restrict__ W2,
    const float* __restrict__ b2, const float* __restrict__ w3,
    const float* __restrict__ h_intent, float* __restrict__ hf_out) {
  const int b = blockIdx.x;
  const int t = threadIdx.x;
  const int lane = t & 63, w = t >> 6;
  __shared__ float hi[50][128];
  __shared__ float outb[50][128];
  __shared__ float att[50][50];
  __shared__ float hsb[128], hsrb[128], q2b[128];
  __shared__ float cj1[50], cj2[50], alb[50];
  __shared__ float tmp2[2][128];
  __shared__ float wred[4][32];

  float mfs = 0.f;
  for (int l = 0; l < 50; l++) mfs += (float)masks[b * 50 + l];

  for (int i = t; i < 50 * 32; i += 256) {
    int r = i >> 5, c4 = (i & 31) << 2;
    int it = items[b * 50 + r];
    *(float4*)&hi[r][c4] = *(const float4*)(item_w + (size_t)it * 128 + c4);
  }
  {
    int d = t & 127, lh = t >> 7;
    float acc = 0.f;
    for (int l = lh; l < 50; l += 2) {
      float m = (float)masks[b * 50 + l];
      int row = inputs[b * 50 + l];
      acc += m * item_w[(size_t)row * 128 + d];
    }
    tmp2[lh][d] = acc;
  }
  __syncthreads();
  if (t < 128) hsb[t] = (tmp2[0][t] + tmp2[1][t]) / mfs;
  __syncthreads();
  {
    float2 lb1v = ((const float2*)lb1)[lane];
    float2 lb2v = ((const float2*)lb2)[lane];
    float2 hs2 = *(const float2*)&hsb[2 * lane];
    for (int j = w; j < 50; j += 4) {
      float2 xj = *(const float2*)&hi[j][2 * lane];
      float s1 = hs2.x * xj.x * lb1v.x + hs2.y * xj.y * lb1v.y;
      float s2 = hs2.x * xj.x * lb2v.x + hs2.y * xj.y * lb2v.y;
#pragma unroll
      for (int o = 32; o; o >>= 1) {
        s1 += __shfl_xor(s1, o, 64);
        s2 += __shfl_xor(s2, o, 64);
      }
      if (lane == 0) { cj1[j] = s1; cj2[j] = s2; }
    }
  }
  __syncthreads();
  {
    float2 la1v = ((const float2*)la1)[lane];
    float2 la2v = ((const float2*)la2)[lane];
    for (int i = w; i < 50; i += 4) {
      float2 xi = *(const float2*)&hi[i][2 * lane];
      float px1 = xi.x * la1v.x, py1 = xi.y * la1v.y;
      float px2 = xi.x * la2v.x, py2 = xi.y * la2v.y;
      for (int j = 0; j < 50; j++) {
        float2 xj = *(const float2*)&hi[j][2 * lane];
        float s1 = px1 * xj.x + py1 * xj.y;
        float s2 = px2 * xj.x + py2 * xj.y;
#pragma unroll
        for (int o = 32; o; o >>= 1) {
          s1 += __shfl_xor(s1, o, 64);
          s2 += __shfl_xor(s2, o, 64);
        }
        if (lane == 0) {
          int a = Aadj[((size_t)b * 50 + i) * 50 + j];
          float v;
          if (a == 1) { float x = s1 + cj1[j]; v = x >= 0.f ? x : 0.2f * x; }
          else if (a == 2) { float x = s2 + cj2[j]; v = x >= 0.f ? x : 0.2f * x; }
          else v = -9e15f;
          att[i][j] = v;
        }
      }
    }
  }
  __syncthreads();
  for (int i = w; i < 50; i += 4) {
    float v = lane < 50 ? att[i][lane] : -INFINITY;
    float mx = v;
#pragma unroll
    for (int o = 32; o; o >>= 1) mx = fmaxf(mx, __shfl_xor(mx, o, 64));
    float ex = lane < 50 ? expf(v - mx) : 0.f;
    float sm = ex;
#pragma unroll
    for (int o = 32; o; o >>= 1) sm += __shfl_xor(sm, o, 64);
    if (lane < 50) att[i][lane] = ex / sm;
  }
  __syncthreads();
  for (int i = w; i < 50; i += 4) {
    float ax = 0.f, ay = 0.f;
    for (int j = 0; j < 50; j++) {
      float a = att[i][j];
      float2 xj = *(const float2*)&hi[j][2 * lane];
      ax = fmaf(a, xj.x, ax);
      ay = fmaf(a, xj.y, ay);
    }
    float2 hv = ((const float2*)(h_intent + ((size_t)b * 50 + i) * 128))[lane];
    *(float2*)&outb[i][2 * lane] =
        make_float2(ax + hv.x + ax * hv.x, ay + hv.y + ay * hv.y);
  }
  __syncthreads();
  for (int i = t; i < 50 * 64; i += 256) {
    int r = i >> 6, c2 = (i & 63) << 1;
    int a = alias_inp[b * 50 + r];
    *(float2*)&hi[r][c2] = *(const float2*)&outb[a][c2];
  }
  __syncthreads();
  for (int i = t; i < 50 * 64; i += 256) {
    int r = i >> 6, c2 = (i & 63) << 1;
    float2 s = *(const float2*)&hi[r][c2];
    float2 p = *(const float2*)(pos_emb + (size_t)r * 128 + c2);
    *(float2*)&outb[r][c2] = make_float2(s.x + p.x, s.y + p.y);
  }
  __syncthreads();
  {
    int d = t & 127, lh = t >> 7;
    float acc = 0.f;
    for (int l = lh; l < 50; l += 2) acc += (float)masks[b * 50 + l] * outb[l][d];
    tmp2[lh][d] = acc;
  }
  __syncthreads();
  if (t < 128) hsrb[t] = (tmp2[0][t] + tmp2[1][t]) / mfs;
  __syncthreads();
  {
    int d = t & 127, kh = t >> 7;
    float acc = 0.f;
    for (int k = kh * 64; k < kh * 64 + 64; k++)
      acc = fmaf(hsrb[k], W2[(size_t)k * 128 + d], acc);
    tmp2[kh][d] = acc;
  }
  __syncthreads();
  if (t < 128) q2b[t] = b2[t] + tmp2[0][t] + tmp2[1][t];
  __syncthreads();
  {
    int d = t & 127, lh = t >> 7;
    float accq[25];
#pragma unroll
    for (int jj = 0; jj < 25; jj++) accq[jj] = b1[d];
    for (int k = 0; k < 128; k += 2) {
      float w1a = W1[(size_t)k * 128 + d];
      float w1b = W1[(size_t)(k + 1) * 128 + d];
#pragma unroll
      for (int jj = 0; jj < 25; jj++) {
        int l = lh + 2 * jj;
        float2 hv = *(const float2*)&outb[l][k];
        accq[jj] = fmaf(hv.x, w1a, accq[jj]);
        accq[jj] = fmaf(hv.y, w1b, accq[jj]);
      }
    }
    float w3v = w3[d], q2v = q2b[d];
#pragma unroll
    for (int jj = 0; jj < 25; jj++) {
      float s = 1.f / (1.f + expf(-(accq[jj] + q2v))) * w3v;
#pragma unroll
      for (int o = 32; o; o >>= 1) s += __shfl_xor(s, o, 64);
      if (lane == 0) wred[w][jj] = s;
    }
  }
  __syncthreads();
  if (t < 50) {
    int l = t, jj = l >> 1;
    alb[l] = (l & 1) ? (wred[2][jj] + wred[3][jj]) : (wred[0][jj] + wred[1][jj]);
  }
  __syncthreads();
  if (t < 128) {
    int d = t;
    float acc = 0.f, pacc = 0.f;
    for (int l = 0; l < 50; l++) {
      float m = (float)masks[b * 50 + l];
      acc += alb[l] * hi[l][d] * m;
      pacc += pos_emb[(size_t)l * 128 + d] * m;
    }
    hf_out[(size_t)b * 128 + d] = acc + pos_emb[50 * 128 + d] * (pacc / mfs);
  }
}

extern "C" void kernel_launch(void* const* d_in, const int* in_sizes, int n_in,
                              void* d_out, int out_size, void* d_ws, size_t ws_size,
                              hipStream_t stream) {
  const int* items = (const int*)d_in[0];
  const int* Aadj = (const int*)d_in[1];
  const int* inputs = (const int*)d_in[2];
  const int* masks = (const int*)d_in[3];
  const int* alias = (const int*)d_in[4];
  const float* item_emb = (const float*)d_in[5];
  const float* intent_emb = (const float*)d_in[6];
  const float* pos_emb = (const float*)d_in[7];
  const float* lq = (const float*)d_in[8];
  const float* lk = (const float*)d_in[9];
  const float* la = (const float*)d_in[10];
  const float* lb = (const float*)d_in[11];
  const float* la1 = (const float*)d_in[12];
  const float* la2 = (const float*)d_in[13];
  const float* lb1 = (const float*)d_in[14];
  const float* lb2 = (const float*)d_in[15];
  const float* W1 = (const float*)d_in[16];
  const float* b1 = (const float*)d_in[17];
  const float* W2 = (const float*)d_in[18];
  const float* b2 = (const float*)d_in[19];
  const float* w3 = (const float*)d_in[20];
  float* out = (float*)d_out;

  char* p = (char*)d_ws;
  auto alloc = [&](size_t bytes) {
    char* r = p;
    p += (bytes + 511) & ~(size_t)511;
    return r;
  };
  float* item_w = (float*)alloc(100000ull * 128 * 4);
  unsigned short* itp = (unsigned short*)alloc(100104ull * 384 * 2);  // [hi|hi|lo], padded rows
  unsigned short* gtp = (unsigned short*)alloc(1024ull * 384 * 2);    // [hi|lo|hi]
  float* intw = (float*)alloc(1024ull * 128 * 4);
  float* CK = (float*)alloc(1024ull * 128 * 4);
  float* Gt = (float*)alloc(1024ull * 128 * 4);
  float* lkT = (float*)alloc(128 * 128 * 4);
  int* idx3 = (int*)alloc(300000ull * 4);
  int* cnt = (int*)alloc(1024 * 4);
  int* offs = (int*)alloc(1025 * 4);
  int* cur = (int*)alloc(1024 * 4);
  int* edge_item = (int*)alloc(300000ull * 4);
  char* big = alloc(13107200);  // overlay: pi4 (12.8MB) then h_int (13.1MB)
  int* pi4 = (int*)big;
  float* h_int = (float*)big;
  float* hf = (float*)alloc(512 * 128 * 4);
  float* hfp_f = (float*)alloc(512ull * 384 * 2);
  unsigned short* hfp = (unsigned short*)hfp_f;

  // prep: normalize + bf16 splits; CK = intw@lk; Gt = CK@lq^T (P eliminated algebraically)
  k_prep_item<<<25000, 256, 0, stream>>>(item_emb, item_w, itp, 100000);
  k_norm<<<256, 256, 0, stream>>>(intent_emb, intw, 1024);
  k_t128<<<1, 256, 0, stream>>>(lk, lkT);
  k_gemm_abt<<<dim3(3, 16), 256, 0, stream>>>(intw, lkT, CK, 1024, 128);
  k_gemm_abt<<<dim3(3, 16), 256, 0, stream>>>(CK, lq, Gt, 1024, 128);
  k_split<<<256, 256, 0, stream>>>(Gt, gtp, 1024);

  // sim + candidate top-4 per 128-col chunk, then exact rescore -> idx3
  k_mfma<0><<<6272, 256, 0, stream>>>(itp, gtp, nullptr, 0, 1024, pi4, 100000);
  k_rescore<<<25000, 256, 0, stream>>>(pi4, item_w, Gt, idx3, 100000);

  hipMemsetAsync(cnt, 0, 1024 * 4, stream);
  k_count<<<(300000 + 255) / 256, 256, 0, stream>>>(idx3, cnt, 300000);
  k_scan<<<1, 1024, 0, stream>>>(cnt, offs, cur);
  k_scatter<<<(300000 + 255) / 256, 256, 0, stream>>>(idx3, cur, edge_item, 300000);
  k_intent<<<1024, 256, 0, stream>>>(item_w, intw, la, offs, edge_item, intw == nullptr ? nullptr : (float*)CK);
  // NOTE: k_intent writes intent_new into CK buffer (CK dead after Gt computed)
  k_hintent<<<6400, 256, 0, stream>>>(items, item_w, idx3, (float*)CK, lb, h_int, 25600);
  k_session<<<512, 256, 0, stream>>>(items, Aadj, inputs, masks, alias, item_w, pos_emb,
                                     la1, la2, lb1, lb2, W1, b1, W2, b2, w3, h_int, hf);
  k_split<<<128, 256, 0, stream>>>(hf, hfp, 512);
  k_mfma<1><<<3136, 256, 0, stream>>>(hfp, itp + 384, out, 99999, 99999, nullptr, 512);
}

// Round 3
// 1351.109 us; speedup vs baseline: 1.9022x; 1.2974x over previous
//
#include <hip/hip_runtime.h>
#include <math.h>

typedef __attribute__((ext_vector_type(4))) float f32x4;
typedef __attribute__((ext_vector_type(8))) short bf16x8;

static __device__ __forceinline__ unsigned short f2bf(float f) {
  unsigned int u = __float_as_uint(f);
  unsigned int r = (u + 0x7FFFu + ((u >> 16) & 1u)) >> 16;
  return (unsigned short)r;
}
static __device__ __forceinline__ float bf2f(unsigned short h) {
  return __uint_as_float(((unsigned int)h) << 16);
}

#define INS3(vv, cc) do { float _v=(vv); int _c=(cc); \
  if (_v > v2) { if (_v > v1) { v2=v1; c2=c1i; if (_v > v0) { v1=v0; c1i=c0; v0=_v; c0=_c; } \
  else { v1=_v; c1i=_c; } } else { v2=_v; c2=_c; } } } while(0)

#define INS4(vv, cc) do { float _v=(vv); int _c=(cc); \
  if (_v > w3v) { if (_v > w1v) { if (_v > w0v) { w3v=w2v;d3=d2; w2v=w1v;d2=d1; w1v=w0v;d1=d0; w0v=_v;d0=_c; } \
    else { w3v=w2v;d3=d2; w2v=w1v;d2=d1; w1v=_v;d1=_c; } } \
    else { if (_v > w2v) { w3v=w2v;d3=d2; w2v=_v;d2=_c; } else { w3v=_v; d3=_c; } } } } while(0)

// ---------------- intents: normalize ----------------
__global__ __launch_bounds__(256) void k_norm(const float* __restrict__ in,
                                              float* __restrict__ out, int R) {
  int g = (blockIdx.x * 256 + threadIdx.x) >> 6;
  int lane = threadIdx.x & 63;
  if (g >= R) return;
  float2 v = ((const float2*)(in + (size_t)g * 128))[lane];
  float ss = v.x * v.x + v.y * v.y;
#pragma unroll
  for (int o = 32; o; o >>= 1) ss += __shfl_xor(ss, o, 64);
  float s = 1.0f / sqrtf(ss);
  ((float2*)(out + (size_t)g * 128))[lane] = make_float2(v.x * s, v.y * s);
}

// ---------------- items: normalize + write fp32 + split [hi|hi|lo] ----------------
__global__ __launch_bounds__(256) void k_prep_item(const float* __restrict__ in,
                                                   float* __restrict__ item_w,
                                                   unsigned short* __restrict__ itp, int R) {
  int g = (blockIdx.x * 256 + threadIdx.x) >> 6;
  int lane = threadIdx.x & 63;
  if (g >= R) return;
  float2 v = ((const float2*)(in + (size_t)g * 128))[lane];
  float ss = v.x * v.x + v.y * v.y;
#pragma unroll
  for (int o = 32; o; o >>= 1) ss += __shfl_xor(ss, o, 64);
  float s = 1.0f / sqrtf(ss);
  float x = v.x * s, y = v.y * s;
  ((float2*)(item_w + (size_t)g * 128))[lane] = make_float2(x, y);
  unsigned short hx = f2bf(x), hy = f2bf(y);
  unsigned short lx = f2bf(x - bf2f(hx)), ly = f2bf(y - bf2f(hy));
  unsigned short* row = itp + (size_t)g * 384;
  ((ushort2*)row)[lane] = make_ushort2(hx, hy);
  ((ushort2*)(row + 128))[lane] = make_ushort2(hx, hy);
  ((ushort2*)(row + 256))[lane] = make_ushort2(lx, ly);
}

// ---------------- generic split [hi|lo|hi] ----------------
__global__ __launch_bounds__(256) void k_split(const float* __restrict__ in,
                                               unsigned short* __restrict__ outp, int R) {
  int g = (blockIdx.x * 256 + threadIdx.x) >> 6;
  int lane = threadIdx.x & 63;
  if (g >= R) return;
  float2 v = ((const float2*)(in + (size_t)g * 128))[lane];
  unsigned short hx = f2bf(v.x), hy = f2bf(v.y);
  unsigned short lx = f2bf(v.x - bf2f(hx)), ly = f2bf(v.y - bf2f(hy));
  unsigned short* row = outp + (size_t)g * 384;
  ((ushort2*)row)[lane] = make_ushort2(hx, hy);
  ((ushort2*)(row + 128))[lane] = make_ushort2(lx, ly);
  ((ushort2*)(row + 256))[lane] = make_ushort2(hx, hy);
}

// ---------------- 128x128 transpose ----------------
__global__ __launch_bounds__(256) void k_t128(const float* __restrict__ in,
                                              float* __restrict__ out) {
  for (int i = threadIdx.x; i < 128 * 128; i += 256) {
    int k = i >> 7, j = i & 127;
    out[j * 128 + k] = in[i];
  }
}

// ---------------- small fp32 C[MxN] = A[Mx128] @ B[Nx128]^T ----------------
__global__ __launch_bounds__(256) void k_gemm_abt(const float* __restrict__ A,
                                                  const float* __restrict__ B,
                                                  float* __restrict__ C, int M, int N) {
  __shared__ float As[64][132];
  __shared__ float Bs[48][132];
  const int t = threadIdx.x;
  const int m0 = blockIdx.y * 64, n0 = blockIdx.x * 48;
  for (int i = t; i < 64 * 32; i += 256) {
    int r = i >> 5, c4 = (i & 31) << 2;
    float4 v = make_float4(0.f, 0.f, 0.f, 0.f);
    if (m0 + r < M) v = *(const float4*)(A + (size_t)(m0 + r) * 128 + c4);
    *(float4*)&As[r][c4] = v;
  }
  for (int i = t; i < 48 * 32; i += 256) {
    int r = i >> 5, c4 = (i & 31) << 2;
    float4 v = make_float4(0.f, 0.f, 0.f, 0.f);
    if (n0 + r < N) v = *(const float4*)(B + (size_t)(n0 + r) * 128 + c4);
    *(float4*)&Bs[r][c4] = v;
  }
  __syncthreads();
  const int ty = t >> 4, tx = t & 15;
  float acc[4][3];
#pragma unroll
  for (int i = 0; i < 4; i++)
#pragma unroll
    for (int j = 0; j < 3; j++) acc[i][j] = 0.f;
#pragma unroll 4
  for (int k = 0; k < 128; k += 4) {
    float4 a[4], b[3];
#pragma unroll
    for (int i = 0; i < 4; i++) a[i] = *(const float4*)&As[ty + 16 * i][k];
#pragma unroll
    for (int j = 0; j < 3; j++) b[j] = *(const float4*)&Bs[tx + 16 * j][k];
#pragma unroll
    for (int i = 0; i < 4; i++)
#pragma unroll
      for (int j = 0; j < 3; j++) {
        float s = acc[i][j];
        s = fmaf(a[i].x, b[j].x, s);
        s = fmaf(a[i].y, b[j].y, s);
        s = fmaf(a[i].z, b[j].z, s);
        s = fmaf(a[i].w, b[j].w, s);
        acc[i][j] = s;
      }
  }
#pragma unroll
  for (int i = 0; i < 4; i++) {
    int m = m0 + ty + 16 * i;
    if (m >= M) continue;
#pragma unroll
    for (int j = 0; j < 3; j++) {
      int n = n0 + tx + 16 * j;
      if (n < N) C[(size_t)m * N + n] = acc[i][j];
    }
  }
}

// ---------------- MFMA split-bf16 GEMM: C[M x N] = A[M x 384] @ B[N x 384]^T ----------------
template <int MODE>
__global__ __launch_bounds__(256, 2) void k_mfma(const unsigned short* __restrict__ Abase,
                                                 const unsigned short* __restrict__ Bbase,
                                                 float* __restrict__ C, int ldc, int Nc,
                                                 int* __restrict__ pi4, int Mv) {
  __shared__ __align__(16) char lds[32768];
  const int t = threadIdx.x, l = t & 63, w = t >> 6;
  const int wr = w >> 1, wc = w & 1;

  int m0, n0, chunk = 0;
  {
    int g = blockIdx.x;
    int xcd = g & 7, r = g >> 3;
    if (MODE == 0) {
      chunk = r & 7;
      int mt = (r >> 3) * 8 + xcd;
      if (mt >= ((Mv + 127) >> 7)) return;
      m0 = mt << 7;
      n0 = chunk << 7;
    } else {
      int mq = r & 3;
      int nt = (r >> 2) * 8 + xcd;
      if (nt >= ((Nc + 127) >> 7)) return;
      m0 = mq << 7;
      n0 = nt << 7;
    }
  }
  const unsigned short* A = Abase + (size_t)m0 * 384;
  const unsigned short* B = Bbase + (size_t)n0 * 384;

  const int r1 = t >> 2, c1 = t & 3;
  f32x4 acc[4][4];
  {
    f32x4 z = {0.f, 0.f, 0.f, 0.f};
#pragma unroll
    for (int i = 0; i < 4; i++)
#pragma unroll
      for (int j = 0; j < 4; j++) acc[i][j] = z;
  }

  int4 sa0, sa1, sb0, sb1;
  {
    sa0 = *(const int4*)(A + (size_t)r1 * 384 + c1 * 8);
    sa1 = *(const int4*)(A + (size_t)(r1 + 64) * 384 + c1 * 8);
    sb0 = *(const int4*)(B + (size_t)r1 * 384 + c1 * 8);
    sb1 = *(const int4*)(B + (size_t)(r1 + 64) * 384 + c1 * 8);
  }

  for (int kt = 0; kt < 12; ++kt) {
    if (kt) __syncthreads();
    *(int4*)(lds + r1 * 80 + c1 * 16) = sa0;
    *(int4*)(lds + (r1 + 64) * 80 + c1 * 16) = sa1;
    *(int4*)(lds + 10240 + r1 * 80 + c1 * 16) = sb0;
    *(int4*)(lds + 10240 + (r1 + 64) * 80 + c1 * 16) = sb1;
    __syncthreads();
    if (kt < 11) {
      const unsigned short* ka = A + (kt + 1) * 32;
      const unsigned short* kb = B + (kt + 1) * 32;
      sa0 = *(const int4*)(ka + (size_t)r1 * 384 + c1 * 8);
      sa1 = *(const int4*)(ka + (size_t)(r1 + 64) * 384 + c1 * 8);
      sb0 = *(const int4*)(kb + (size_t)r1 * 384 + c1 * 8);
      sb1 = *(const int4*)(kb + (size_t)(r1 + 64) * 384 + c1 * 8);
    }
    bf16x8 af[4], bfr[4];
#pragma unroll
    for (int i = 0; i < 4; i++) {
      int ar = wr * 64 + i * 16 + (l & 15);
      af[i] = *(const bf16x8*)(lds + ar * 80 + (l >> 4) * 16);
      int br = wc * 64 + i * 16 + (l & 15);
      bfr[i] = *(const bf16x8*)(lds + 10240 + br * 80 + (l >> 4) * 16);
    }
#pragma unroll
    for (int i = 0; i < 4; i++)
#pragma unroll
      for (int j = 0; j < 4; j++)
        acc[i][j] = __builtin_amdgcn_mfma_f32_16x16x32_bf16(af[i], bfr[j], acc[i][j], 0, 0, 0);
  }

  if (MODE == 1) {
#pragma unroll
    for (int i = 0; i < 4; i++)
#pragma unroll
      for (int q = 0; q < 4; q++) {
        int m = m0 + wr * 64 + i * 16 + (l >> 4) * 4 + q;
#pragma unroll
        for (int j = 0; j < 4; j++) {
          int n = n0 + wc * 64 + j * 16 + (l & 15);
          if (n < Nc) C[(size_t)m * ldc + n] = acc[i][j][q];
        }
      }
  } else {
    __syncthreads();
    float* sp = (float*)lds;
#pragma unroll
    for (int i = 0; i < 4; i++)
#pragma unroll
      for (int q = 0; q < 4; q++) {
        float va = -3.0e38f, vb = -3.0e38f;
        int ja = 0, jb = 0;
#pragma unroll
        for (int j = 0; j < 4; j++) {
          float v = acc[i][j][q];
          if (v > vb) {
            if (v > va) { vb = va; jb = ja; va = v; ja = j; }
            else { vb = v; jb = j; }
          }
        }
        int row = wr * 64 + i * 16 + (l >> 4) * 4 + q;
        int contrib = wc * 16 + (l & 15);
        sp[(row * 32 + contrib) * 2] =
            __uint_as_float((__float_as_uint(va) & ~3u) | (unsigned)ja);
        sp[(row * 32 + contrib) * 2 + 1] =
            __uint_as_float((__float_as_uint(vb) & ~3u) | (unsigned)jb);
      }
    __syncthreads();
    if (t < 128) {
      int grow = m0 + t;
      if (grow < Mv) {
        float w0v = -3.0e38f, w1v = -3.0e38f, w2v = -3.0e38f, w3v = -3.0e38f;
        int d0 = 0, d1 = 0, d2 = 0, d3 = 0;
        for (int cbt = 0; cbt < 64; cbt++) {
          float v = sp[t * 64 + cbt];
          int contrib = cbt >> 1;
          int j = (int)(__float_as_uint(v) & 3u);
          int col = n0 + (contrib >> 4) * 64 + j * 16 + (contrib & 15);
          INS4(v, col);
        }
        size_t pb = (size_t)grow * 32 + chunk * 4;
        pi4[pb] = d0; pi4[pb + 1] = d1; pi4[pb + 2] = d2; pi4[pb + 3] = d3;
      }
    }
  }
}

// ---- exact fp32 rescore -> top-3 intents; fused e1 computation + intent counting ----
__global__ __launch_bounds__(256) void k_rescore(const int* __restrict__ pi4,
                                                 const float* __restrict__ item_w,
                                                 const float* __restrict__ Gt,
                                                 const float* __restrict__ intw,
                                                 const float* __restrict__ la,
                                                 int* __restrict__ idx3,
                                                 float* __restrict__ e1vals,
                                                 int* __restrict__ cnt, int M) {
  int r = (blockIdx.x * 256 + threadIdx.x) >> 6;
  int l = threadIdx.x & 63;
  if (r >= M) return;
  float2 iw = ((const float2*)(item_w + (size_t)r * 128))[l];
  float v0 = -3.0e38f, v1 = -3.0e38f, v2 = -3.0e38f;
  int c0 = 0, c1i = 0, c2 = 0;
  for (int s = 0; s < 32; s++) {
    int c = pi4[(size_t)r * 32 + s];
    float2 g = ((const float2*)(Gt + (size_t)c * 128))[l];
    float d = iw.x * g.x + iw.y * g.y;
#pragma unroll
    for (int o = 32; o; o >>= 1) d += __shfl_xor(d, o, 64);
    INS3(d, c);
  }
  // e1 for the 3 chosen intents: lrelu( sum iw * (cw * la) )
  float2 lav = ((const float2*)la)[l];
  float e1v[3];
  int cs[3] = {c0, c1i, c2};
#pragma unroll
  for (int k = 0; k < 3; k++) {
    float2 cw = ((const float2*)(intw + (size_t)cs[k] * 128))[l];
    float d = iw.x * (cw.x * lav.x) + iw.y * (cw.y * lav.y);
#pragma unroll
    for (int o = 32; o; o >>= 1) d += __shfl_xor(d, o, 64);
    e1v[k] = d >= 0.f ? d : 0.2f * d;
  }
  if (l == 0) {
    idx3[r * 3] = c0; idx3[r * 3 + 1] = c1i; idx3[r * 3 + 2] = c2;
    e1vals[r * 3] = e1v[0]; e1vals[r * 3 + 1] = e1v[1]; e1vals[r * 3 + 2] = e1v[2];
    atomicAdd(&cnt[c0], 1); atomicAdd(&cnt[c1i], 1); atomicAdd(&cnt[c2], 1);
  }
}

__global__ __launch_bounds__(1024) void k_scan(const int* __restrict__ cnt,
                                               int* __restrict__ offs,
                                               int* __restrict__ cur) {
  __shared__ int s[1024];
  int t = threadIdx.x;
  int own = cnt[t];
  s[t] = own;
  __syncthreads();
  for (int o = 1; o < 1024; o <<= 1) {
    int v = (t >= o) ? s[t - o] : 0;
    __syncthreads();
    s[t] += v;
    __syncthreads();
  }
  int excl = s[t] - own;
  offs[t] = excl;
  cur[t] = excl;
  if (t == 1023) offs[1024] = s[1023];
}

__global__ void k_scatter(const int* __restrict__ idx3, int* __restrict__ cur,
                          int* __restrict__ edge_id, int E) {
  int e = blockIdx.x * 256 + threadIdx.x;
  if (e < E) {
    int c = idx3[e];
    int pos = atomicAdd(&cur[c], 1);
    edge_id[pos] = e;  // original edge id (item = e/3, e1 = e1vals[e])
  }
}

// ---------------- per-intent softmax-weighted item gather (single pass) ----------------
__global__ __launch_bounds__(512) void k_intent(const float* __restrict__ item_w,
                                                const float* __restrict__ e1vals,
                                                const int* __restrict__ offs,
                                                const int* __restrict__ edge_id,
                                                float* __restrict__ intent_new) {
  int c = blockIdx.x;
  int start = offs[c], end = offs[c + 1];
  int t = threadIdx.x, lane = t & 63, w = t >> 6;
  __shared__ float smx[8], sden[8], sacc[8][128];
  // phase 1: segment max over e1 (scalar gather)
  float mx = -3.0e38f;
  for (int e = start + t; e < end; e += 512) mx = fmaxf(mx, e1vals[edge_id[e]]);
#pragma unroll
  for (int o = 32; o; o >>= 1) mx = fmaxf(mx, __shfl_xor(mx, o, 64));
  if (lane == 0) smx[w] = mx;
  __syncthreads();
  mx = smx[0];
#pragma unroll
  for (int i = 1; i < 8; i++) mx = fmaxf(mx, smx[i]);
  // phase 2: weighted row gather, 8 waves x 4-deep unroll
  float ax = 0.f, ay = 0.f, den = 0.f;
  int e = start + w;
  for (; e + 24 < end; e += 32) {
    int e0 = edge_id[e], e1 = edge_id[e + 8], e2 = edge_id[e + 16], e3 = edge_id[e + 24];
    float2 r0 = ((const float2*)(item_w + (size_t)((unsigned)e0 / 3u) * 128))[lane];
    float2 r1 = ((const float2*)(item_w + (size_t)((unsigned)e1 / 3u) * 128))[lane];
    float2 r2 = ((const float2*)(item_w + (size_t)((unsigned)e2 / 3u) * 128))[lane];
    float2 r3 = ((const float2*)(item_w + (size_t)((unsigned)e3 / 3u) * 128))[lane];
    float w0 = expf(e1vals[e0] - mx), w1 = expf(e1vals[e1] - mx);
    float w2 = expf(e1vals[e2] - mx), w3 = expf(e1vals[e3] - mx);
    ax = fmaf(w0, r0.x, fmaf(w1, r1.x, fmaf(w2, r2.x, fmaf(w3, r3.x, ax))));
    ay = fmaf(w0, r0.y, fmaf(w1, r1.y, fmaf(w2, r2.y, fmaf(w3, r3.y, ay))));
    den += w0 + w1 + w2 + w3;
  }
  for (; e < end; e += 8) {
    int e0 = edge_id[e];
    float2 r0 = ((const float2*)(item_w + (size_t)((unsigned)e0 / 3u) * 128))[lane];
    float w0 = expf(e1vals[e0] - mx);
    ax = fmaf(w0, r0.x, ax);
    ay = fmaf(w0, r0.y, ay);
    den += w0;
  }
  sacc[w][2 * lane] = ax;
  sacc[w][2 * lane + 1] = ay;
  if (lane == 0) sden[w] = den;
  __syncthreads();
  if (t < 128) {
    float s = 0.f;
#pragma unroll
    for (int i = 0; i < 8; i++) s += sacc[i][t];
    float dt = 0.f;
#pragma unroll
    for (int i = 0; i < 8; i++) dt += sden[i];
    float inv = dt > 0.f ? 1.f / dt : 0.f;
    intent_new[(size_t)c * 128 + t] = s * inv;
  }
}

// ---------------- h_intent for the referenced (b,n) items ----------------
__global__ __launch_bounds__(256) void k_hintent(const int* __restrict__ items,
                                                 const float* __restrict__ item_w,
                                                 const int* __restrict__ idx3,
                                                 const float* __restrict__ intent_new,
                                                 const float* __restrict__ lb,
                                                 float* __restrict__ h_intent, int total) {
  int g = (blockIdx.x * 256 + threadIdx.x) >> 6;
  int lane = threadIdx.x & 63;
  if (g >= total) return;
  int it = items[g];
  float2 iw = ((const float2*)(item_w + (size_t)it * 128))[lane];
  float2 lbv = ((const float2*)lb)[lane];
  float e2[3];
  float2 nb[3];
#pragma unroll
  for (int k = 0; k < 3; k++) {
    int c = idx3[(size_t)it * 3 + k];
    nb[k] = ((const float2*)(intent_new + (size_t)c * 128))[lane];
    float d = iw.x * nb[k].x * lbv.x + iw.y * nb[k].y * lbv.y;
#pragma unroll
    for (int o = 32; o; o >>= 1) d += __shfl_xor(d, o, 64);
    e2[k] = d >= 0.f ? d : 0.2f * d;
  }
  float m = fmaxf(fmaxf(e2[0], e2[1]), e2[2]);
  float x0 = expf(e2[0] - m), x1 = expf(e2[1] - m), x2 = expf(e2[2] - m);
  float inv = 1.f / (x0 + x1 + x2);
  float nx = (x0 * nb[0].x + x1 * nb[1].x + x2 * nb[2].x) * inv;
  float ny = (x0 * nb[0].y + x1 * nb[1].y + x2 * nb[2].y) * inv;
  ((float2*)(h_intent + (size_t)g * 128))[lane] =
      make_float2(0.5f * iw.x + 0.5f * nx, 0.5f * iw.y + 0.5f * ny);
}

// ---------------- fused per-session local graph + readout -> hf ----------------
__global__ __launch_bounds__(256) void k_session(
    const int* __restrict__ items, const int* __restrict__ Aadj,
    const int* __restrict__ inputs, const int* __restrict__ masks,
    const int* __restrict__ alias_inp, const float* __restrict__ item_w,
    const float* __restrict__ pos_emb, const float* __restrict__ la1,
    const float* __restrict__ la2, const float* __restrict__ lb1,
    const float* __restrict__ lb2, const float* __restrict__ W1,
    const float* __restrict__ b1, const float* __restrict__ W2,
    const float* __restrict__ b2, const float* __restrict__ w3,
    const float* __restrict__ h_intent, float* __restrict__ hf_out) {
  const int b = blockIdx.x;
  const int t = threadIdx.x;
  const int lane = t & 63, w = t >> 6;
  __shared__ float hi[50][128];
  __shared__ float outb[50][128];
  __shared__ float att[50][50];
  __shared__ float hsb[128], hsrb[128], q2b[128];
  __shared__ float cj1[50], cj2[50], alb[50];
  __shared__ float tmp2[2][128];
  __shared__ float wred[4][32];

  float mfs = 0.f;
  for (int l = 0; l < 50; l++) mfs += (float)masks[b * 50 + l];

  for (int i = t; i < 50 * 32; i += 256) {
    int r = i >> 5, c4 = (i & 31) << 2;
    int it = items[b * 50 + r];
    *(float4*)&hi[r][c4] = *(const float4*)(item_w + (size_t)it * 128 + c4);
  }
  {
    int d = t & 127, lh = t >> 7;
    float acc = 0.f;
    for (int l = lh; l < 50; l += 2) {
      float m = (float)masks[b * 50 + l];
      int row = inputs[b * 50 + l];
      acc += m * item_w[(size_t)row * 128 + d];
    }
    tmp2[lh][d] = acc;
  }
  __syncthreads();
  if (t < 128) hsb[t] = (tmp2[0][t] + tmp2[1][t]) / mfs;
  __syncthreads();
  {
    float2 lb1v = ((const float2*)lb1)[lane];
    float2 lb2v = ((const float2*)lb2)[lane];
    float2 hs2 = *(const float2*)&hsb[2 * lane];
    for (int j = w; j < 50; j += 4) {
      float2 xj = *(const float2*)&hi[j][2 * lane];
      float s1 = hs2.x * xj.x * lb1v.x + hs2.y * xj.y * lb1v.y;
      float s2 = hs2.x * xj.x * lb2v.x + hs2.y * xj.y * lb2v.y;
#pragma unroll
      for (int o = 32; o; o >>= 1) {
        s1 += __shfl_xor(s1, o, 64);
        s2 += __shfl_xor(s2, o, 64);
      }
      if (lane == 0) { cj1[j] = s1; cj2[j] = s2; }
    }
  }
  __syncthreads();
  {
    float2 la1v = ((const float2*)la1)[lane];
    float2 la2v = ((const float2*)la2)[lane];
    for (int i = w; i < 50; i += 4) {
      float2 xi = *(const float2*)&hi[i][2 * lane];
      float px1 = xi.x * la1v.x, py1 = xi.y * la1v.y;
      float px2 = xi.x * la2v.x, py2 = xi.y * la2v.y;
      for (int j = 0; j < 50; j++) {
        float2 xj = *(const float2*)&hi[j][2 * lane];
        float s1 = px1 * xj.x + py1 * xj.y;
        float s2 = px2 * xj.x + py2 * xj.y;
#pragma unroll
        for (int o = 32; o; o >>= 1) {
          s1 += __shfl_xor(s1, o, 64);
          s2 += __shfl_xor(s2, o, 64);
        }
        if (lane == 0) {
          int a = Aadj[((size_t)b * 50 + i) * 50 + j];
          float v;
          if (a == 1) { float x = s1 + cj1[j]; v = x >= 0.f ? x : 0.2f * x; }
          else if (a == 2) { float x = s2 + cj2[j]; v = x >= 0.f ? x : 0.2f * x; }
          else v = -9e15f;
          att[i][j] = v;
        }
      }
    }
  }
  __syncthreads();
  for (int i = w; i < 50; i += 4) {
    float v = lane < 50 ? att[i][lane] : -INFINITY;
    float mx = v;
#pragma unroll
    for (int o = 32; o; o >>= 1) mx = fmaxf(mx, __shfl_xor(mx, o, 64));
    float ex = lane < 50 ? expf(v - mx) : 0.f;
    float sm = ex;
#pragma unroll
    for (int o = 32; o; o >>= 1) sm += __shfl_xor(sm, o, 64);
    if (lane < 50) att[i][lane] = ex / sm;
  }
  __syncthreads();
  for (int i = w; i < 50; i += 4) {
    float ax = 0.f, ay = 0.f;
    for (int j = 0; j < 50; j++) {
      float a = att[i][j];
      float2 xj = *(const float2*)&hi[j][2 * lane];
      ax = fmaf(a, xj.x, ax);
      ay = fmaf(a, xj.y, ay);
    }
    float2 hv = ((const float2*)(h_intent + ((size_t)b * 50 + i) * 128))[lane];
    *(float2*)&outb[i][2 * lane] =
        make_float2(ax + hv.x + ax * hv.x, ay + hv.y + ay * hv.y);
  }
  __syncthreads();
  for (int i = t; i < 50 * 64; i += 256) {
    int r = i >> 6, c2 = (i & 63) << 1;
    int a = alias_inp[b * 50 + r];
    *(float2*)&hi[r][c2] = *(const float2*)&outb[a][c2];
  }
  __syncthreads();
  for (int i = t; i < 50 * 64; i += 256) {
    int r = i >> 6, c2 = (i & 63) << 1;
    float2 s = *(const float2*)&hi[r][c2];
    float2 p = *(const float2*)(pos_emb + (size_t)r * 128 + c2);
    *(float2*)&outb[r][c2] = make_float2(s.x + p.x, s.y + p.y);
  }
  __syncthreads();
  {
    int d = t & 127, lh = t >> 7;
    float acc = 0.f;
    for (int l = lh; l < 50; l += 2) acc += (float)masks[b * 50 + l] * outb[l][d];
    tmp2[lh][d] = acc;
  }
  __syncthreads();
  if (t < 128) hsrb[t] = (tmp2[0][t] + tmp2[1][t]) / mfs;
  __syncthreads();
  {
    int d = t & 127, kh = t >> 7;
    float acc = 0.f;
    for (int k = kh * 64; k < kh * 64 + 64; k++)
      acc = fmaf(hsrb[k], W2[(size_t)k * 128 + d], acc);
    tmp2[kh][d] = acc;
  }
  __syncthreads();
  if (t < 128) q2b[t] = b2[t] + tmp2[0][t] + tmp2[1][t];
  __syncthreads();
  {
    int d = t & 127, lh = t >> 7;
    float accq[25];
#pragma unroll
    for (int jj = 0; jj < 25; jj++) accq[jj] = b1[d];
    for (int k = 0; k < 128; k += 2) {
      float w1a = W1[(size_t)k * 128 + d];
      float w1b = W1[(size_t)(k + 1) * 128 + d];
#pragma unroll
      for (int jj = 0; jj < 25; jj++) {
        int l = lh + 2 * jj;
        float2 hv = *(const float2*)&outb[l][k];
        accq[jj] = fmaf(hv.x, w1a, accq[jj]);
        accq[jj] = fmaf(hv.y, w1b, accq[jj]);
      }
    }
    float w3v = w3[d], q2v = q2b[d];
#pragma unroll
    for (int jj = 0; jj < 25; jj++) {
      float s = 1.f / (1.f + expf(-(accq[jj] + q2v))) * w3v;
#pragma unroll
      for (int o = 32; o; o >>= 1) s += __shfl_xor(s, o, 64);
      if (lane == 0) wred[w][jj] = s;
    }
  }
  __syncthreads();
  if (t < 50) {
    int l = t, jj = l >> 1;
    alb[l] = (l & 1) ? (wred[2][jj] + wred[3][jj]) : (wred[0][jj] + wred[1][jj]);
  }
  __syncthreads();
  if (t < 128) {
    int d = t;
    float acc = 0.f, pacc = 0.f;
    for (int l = 0; l < 50; l++) {
      float m = (float)masks[b * 50 + l];
      acc += alb[l] * hi[l][d] * m;
      pacc += pos_emb[(size_t)l * 128 + d] * m;
    }
    hf_out[(size_t)b * 128 + d] = acc + pos_emb[50 * 128 + d] * (pacc / mfs);
  }
}

extern "C" void kernel_launch(void* const* d_in, const int* in_sizes, int n_in,
                              void* d_out, int out_size, void* d_ws, size_t ws_size,
                              hipStream_t stream) {
  const int* items = (const int*)d_in[0];
  const int* Aadj = (const int*)d_in[1];
  const int* inputs = (const int*)d_in[2];
  const int* masks = (const int*)d_in[3];
  const int* alias = (const int*)d_in[4];
  const float* item_emb = (const float*)d_in[5];
  const float* intent_emb = (const float*)d_in[6];
  const float* pos_emb = (const float*)d_in[7];
  const float* lq = (const float*)d_in[8];
  const float* lk = (const float*)d_in[9];
  const float* la = (const float*)d_in[10];
  const float* lb = (const float*)d_in[11];
  const float* la1 = (const float*)d_in[12];
  const float* la2 = (const float*)d_in[13];
  const float* lb1 = (const float*)d_in[14];
  const float* lb2 = (const float*)d_in[15];
  const float* W1 = (const float*)d_in[16];
  const float* b1 = (const float*)d_in[17];
  const float* W2 = (const float*)d_in[18];
  const float* b2 = (const float*)d_in[19];
  const float* w3 = (const float*)d_in[20];
  float* out = (float*)d_out;

  char* p = (char*)d_ws;
  auto alloc = [&](size_t bytes) {
    char* r = p;
    p += (bytes + 511) & ~(size_t)511;
    return r;
  };
  float* item_w = (float*)alloc(100000ull * 128 * 4);
  unsigned short* itp = (unsigned short*)alloc(100104ull * 384 * 2);
  unsigned short* gtp = (unsigned short*)alloc(1024ull * 384 * 2);
  float* intw = (float*)alloc(1024ull * 128 * 4);
  float* CK = (float*)alloc(1024ull * 128 * 4);
  float* Gt = (float*)alloc(1024ull * 128 * 4);
  float* lkT = (float*)alloc(128 * 128 * 4);
  int* idx3 = (int*)alloc(300000ull * 4);
  float* e1vals = (float*)alloc(300000ull * 4);
  int* cnt = (int*)alloc(1024 * 4);
  int* offs = (int*)alloc(1025 * 4);
  int* cur = (int*)alloc(1024 * 4);
  int* edge_id = (int*)alloc(300000ull * 4);
  char* big = alloc(13107200);  // overlay: pi4 (12.8MB) then h_int (13.1MB)
  int* pi4 = (int*)big;
  float* h_int = (float*)big;
  float* hf = (float*)alloc(512 * 128 * 4);
  float* hfp_f = (float*)alloc(512ull * 384 * 2);
  unsigned short* hfp = (unsigned short*)hfp_f;

  k_prep_item<<<25000, 256, 0, stream>>>(item_emb, item_w, itp, 100000);
  k_norm<<<256, 256, 0, stream>>>(intent_emb, intw, 1024);
  k_t128<<<1, 256, 0, stream>>>(lk, lkT);
  k_gemm_abt<<<dim3(3, 16), 256, 0, stream>>>(intw, lkT, CK, 1024, 128);
  k_gemm_abt<<<dim3(3, 16), 256, 0, stream>>>(CK, lq, Gt, 1024, 128);
  k_split<<<256, 256, 0, stream>>>(Gt, gtp, 1024);

  hipMemsetAsync(cnt, 0, 1024 * 4, stream);
  k_mfma<0><<<6272, 256, 0, stream>>>(itp, gtp, nullptr, 0, 1024, pi4, 100000);
  k_rescore<<<25000, 256, 0, stream>>>(pi4, item_w, Gt, intw, la, idx3, e1vals, cnt, 100000);

  k_scan<<<1, 1024, 0, stream>>>(cnt, offs, cur);
  k_scatter<<<(300000 + 255) / 256, 256, 0, stream>>>(idx3, cur, edge_id, 300000);
  k_intent<<<1024, 512, 0, stream>>>(item_w, e1vals, offs, edge_id, (float*)CK);
  k_hintent<<<6400, 256, 0, stream>>>(items, item_w, idx3, (float*)CK, lb, h_int, 25600);
  k_session<<<512, 256, 0, stream>>>(items, Aadj, inputs, masks, alias, item_w, pos_emb,
                                     la1, la2, lb1, lb2, W1, b1, W2, b2, w3, h_int, hf);
  k_split<<<128, 256, 0, stream>>>(hf, hfp, 512);
  k_mfma<1><<<3136, 256, 0, stream>>>(hfp, itp + 384, out, 99999, 99999, nullptr, 512);
}

// Round 5
// 1133.121 us; speedup vs baseline: 2.2681x; 1.1924x over previous
//
#include <hip/hip_runtime.h>
#include <math.h>

typedef __attribute__((ext_vector_type(4))) float f32x4;
typedef __attribute__((ext_vector_type(8))) short bf16x8;

static __device__ __forceinline__ unsigned short f2bf(float f) {
  unsigned int u = __float_as_uint(f);
  unsigned int r = (u + 0x7FFFu + ((u >> 16) & 1u)) >> 16;
  return (unsigned short)r;
}
static __device__ __forceinline__ float bf2f(unsigned short h) {
  return __uint_as_float(((unsigned int)h) << 16);
}

#define INS3(vv, cc) do { float _v=(vv); int _c=(cc); \
  if (_v > v2) { if (_v > v1) { v2=v1; c2=c1i; if (_v > v0) { v1=v0; c1i=c0; v0=_v; c0=_c; } \
  else { v1=_v; c1i=_c; } } else { v2=_v; c2=_c; } } } while(0)

#define INS4(vv, cc) do { float _v=(vv); int _c=(cc); \
  if (_v > w3v) { if (_v > w1v) { if (_v > w0v) { w3v=w2v;d3=d2; w2v=w1v;d2=d1; w1v=w0v;d1=d0; w0v=_v;d0=_c; } \
    else { w3v=w2v;d3=d2; w2v=w1v;d2=d1; w1v=_v;d1=_c; } } \
    else { if (_v > w2v) { w3v=w2v;d3=d2; w2v=_v;d2=_c; } else { w3v=_v; d3=_c; } } } } while(0)

// ---------------- intents: normalize ----------------
__global__ __launch_bounds__(256) void k_norm(const float* __restrict__ in,
                                              float* __restrict__ out, int R) {
  int g = (blockIdx.x * 256 + threadIdx.x) >> 6;
  int lane = threadIdx.x & 63;
  if (g >= R) return;
  float2 v = ((const float2*)(in + (size_t)g * 128))[lane];
  float ss = v.x * v.x + v.y * v.y;
#pragma unroll
  for (int o = 32; o; o >>= 1) ss += __shfl_xor(ss, o, 64);
  float s = 1.0f / sqrtf(ss);
  ((float2*)(out + (size_t)g * 128))[lane] = make_float2(v.x * s, v.y * s);
}

// ---------------- items: normalize + write fp32 + split [hi|hi|lo] ----------------
__global__ __launch_bounds__(256) void k_prep_item(const float* __restrict__ in,
                                                   float* __restrict__ item_w,
                                                   unsigned short* __restrict__ itp, int R) {
  int g = (blockIdx.x * 256 + threadIdx.x) >> 6;
  int lane = threadIdx.x & 63;
  if (g >= R) return;
  float2 v = ((const float2*)(in + (size_t)g * 128))[lane];
  float ss = v.x * v.x + v.y * v.y;
#pragma unroll
  for (int o = 32; o; o >>= 1) ss += __shfl_xor(ss, o, 64);
  float s = 1.0f / sqrtf(ss);
  float x = v.x * s, y = v.y * s;
  ((float2*)(item_w + (size_t)g * 128))[lane] = make_float2(x, y);
  unsigned short hx = f2bf(x), hy = f2bf(y);
  unsigned short lx = f2bf(x - bf2f(hx)), ly = f2bf(y - bf2f(hy));
  unsigned short* row = itp + (size_t)g * 384;
  ((ushort2*)row)[lane] = make_ushort2(hx, hy);
  ((ushort2*)(row + 128))[lane] = make_ushort2(hx, hy);
  ((ushort2*)(row + 256))[lane] = make_ushort2(lx, ly);
}

// ---------------- generic split [hi|lo|hi] ----------------
__global__ __launch_bounds__(256) void k_split(const float* __restrict__ in,
                                               unsigned short* __restrict__ outp, int R) {
  int g = (blockIdx.x * 256 + threadIdx.x) >> 6;
  int lane = threadIdx.x & 63;
  if (g >= R) return;
  float2 v = ((const float2*)(in + (size_t)g * 128))[lane];
  unsigned short hx = f2bf(v.x), hy = f2bf(v.y);
  unsigned short lx = f2bf(v.x - bf2f(hx)), ly = f2bf(v.y - bf2f(hy));
  unsigned short* row = outp + (size_t)g * 384;
  ((ushort2*)row)[lane] = make_ushort2(hx, hy);
  ((ushort2*)(row + 128))[lane] = make_ushort2(lx, ly);
  ((ushort2*)(row + 256))[lane] = make_ushort2(hx, hy);
}

// ---------------- 128x128 transpose ----------------
__global__ __launch_bounds__(256) void k_t128(const float* __restrict__ in,
                                              float* __restrict__ out) {
  for (int i = threadIdx.x; i < 128 * 128; i += 256) {
    int k = i >> 7, j = i & 127;
    out[j * 128 + k] = in[i];
  }
}

// ---------------- small fp32 C[MxN] = A[Mx128] @ B[Nx128]^T ----------------
__global__ __launch_bounds__(256) void k_gemm_abt(const float* __restrict__ A,
                                                  const float* __restrict__ B,
                                                  float* __restrict__ C, int M, int N) {
  __shared__ float As[64][132];
  __shared__ float Bs[48][132];
  const int t = threadIdx.x;
  const int m0 = blockIdx.y * 64, n0 = blockIdx.x * 48;
  for (int i = t; i < 64 * 32; i += 256) {
    int r = i >> 5, c4 = (i & 31) << 2;
    float4 v = make_float4(0.f, 0.f, 0.f, 0.f);
    if (m0 + r < M) v = *(const float4*)(A + (size_t)(m0 + r) * 128 + c4);
    *(float4*)&As[r][c4] = v;
  }
  for (int i = t; i < 48 * 32; i += 256) {
    int r = i >> 5, c4 = (i & 31) << 2;
    float4 v = make_float4(0.f, 0.f, 0.f, 0.f);
    if (n0 + r < N) v = *(const float4*)(B + (size_t)(n0 + r) * 128 + c4);
    *(float4*)&Bs[r][c4] = v;
  }
  __syncthreads();
  const int ty = t >> 4, tx = t & 15;
  float acc[4][3];
#pragma unroll
  for (int i = 0; i < 4; i++)
#pragma unroll
    for (int j = 0; j < 3; j++) acc[i][j] = 0.f;
#pragma unroll 4
  for (int k = 0; k < 128; k += 4) {
    float4 a[4], b[3];
#pragma unroll
    for (int i = 0; i < 4; i++) a[i] = *(const float4*)&As[ty + 16 * i][k];
#pragma unroll
    for (int j = 0; j < 3; j++) b[j] = *(const float4*)&Bs[tx + 16 * j][k];
#pragma unroll
    for (int i = 0; i < 4; i++)
#pragma unroll
      for (int j = 0; j < 3; j++) {
        float s = acc[i][j];
        s = fmaf(a[i].x, b[j].x, s);
        s = fmaf(a[i].y, b[j].y, s);
        s = fmaf(a[i].z, b[j].z, s);
        s = fmaf(a[i].w, b[j].w, s);
        acc[i][j] = s;
      }
  }
#pragma unroll
  for (int i = 0; i < 4; i++) {
    int m = m0 + ty + 16 * i;
    if (m >= M) continue;
#pragma unroll
    for (int j = 0; j < 3; j++) {
      int n = n0 + tx + 16 * j;
      if (n < N) C[(size_t)m * N + n] = acc[i][j];
    }
  }
}

// ---------------- MFMA split-bf16 GEMM: C[M x N] = A[M x 384] @ B[N x 384]^T ----------------
template <int MODE>
__global__ __launch_bounds__(256, 2) void k_mfma(const unsigned short* __restrict__ Abase,
                                                 const unsigned short* __restrict__ Bbase,
                                                 float* __restrict__ C, int ldc, int Nc,
                                                 int* __restrict__ pi4, int Mv) {
  __shared__ __align__(16) char lds[32768];
  const int t = threadIdx.x, l = t & 63, w = t >> 6;
  const int wr = w >> 1, wc = w & 1;

  int m0, n0, chunk = 0;
  {
    int g = blockIdx.x;
    int xcd = g & 7, r = g >> 3;
    if (MODE == 0) {
      chunk = r & 7;
      int mt = (r >> 3) * 8 + xcd;
      if (mt >= ((Mv + 127) >> 7)) return;
      m0 = mt << 7;
      n0 = chunk << 7;
    } else {
      int mq = r & 3;
      int nt = (r >> 2) * 8 + xcd;
      if (nt >= ((Nc + 127) >> 7)) return;
      m0 = mq << 7;
      n0 = nt << 7;
    }
  }
  const unsigned short* A = Abase + (size_t)m0 * 384;
  const unsigned short* B = Bbase + (size_t)n0 * 384;

  const int r1 = t >> 2, c1 = t & 3;
  f32x4 acc[4][4];
  {
    f32x4 z = {0.f, 0.f, 0.f, 0.f};
#pragma unroll
    for (int i = 0; i < 4; i++)
#pragma unroll
      for (int j = 0; j < 4; j++) acc[i][j] = z;
  }

  int4 sa0, sa1, sb0, sb1;
  {
    sa0 = *(const int4*)(A + (size_t)r1 * 384 + c1 * 8);
    sa1 = *(const int4*)(A + (size_t)(r1 + 64) * 384 + c1 * 8);
    sb0 = *(const int4*)(B + (size_t)r1 * 384 + c1 * 8);
    sb1 = *(const int4*)(B + (size_t)(r1 + 64) * 384 + c1 * 8);
  }

  for (int kt = 0; kt < 12; ++kt) {
    if (kt) __syncthreads();
    *(int4*)(lds + r1 * 80 + c1 * 16) = sa0;
    *(int4*)(lds + (r1 + 64) * 80 + c1 * 16) = sa1;
    *(int4*)(lds + 10240 + r1 * 80 + c1 * 16) = sb0;
    *(int4*)(lds + 10240 + (r1 + 64) * 80 + c1 * 16) = sb1;
    __syncthreads();
    if (kt < 11) {
      const unsigned short* ka = A + (kt + 1) * 32;
      const unsigned short* kb = B + (kt + 1) * 32;
      sa0 = *(const int4*)(ka + (size_t)r1 * 384 + c1 * 8);
      sa1 = *(const int4*)(ka + (size_t)(r1 + 64) * 384 + c1 * 8);
      sb0 = *(const int4*)(kb + (size_t)r1 * 384 + c1 * 8);
      sb1 = *(const int4*)(kb + (size_t)(r1 + 64) * 384 + c1 * 8);
    }
    bf16x8 af[4], bfr[4];
#pragma unroll
    for (int i = 0; i < 4; i++) {
      int ar = wr * 64 + i * 16 + (l & 15);
      af[i] = *(const bf16x8*)(lds + ar * 80 + (l >> 4) * 16);
      int br = wc * 64 + i * 16 + (l & 15);
      bfr[i] = *(const bf16x8*)(lds + 10240 + br * 80 + (l >> 4) * 16);
    }
#pragma unroll
    for (int i = 0; i < 4; i++)
#pragma unroll
      for (int j = 0; j < 4; j++)
        acc[i][j] = __builtin_amdgcn_mfma_f32_16x16x32_bf16(af[i], bfr[j], acc[i][j], 0, 0, 0);
  }

  if (MODE == 1) {
#pragma unroll
    for (int i = 0; i < 4; i++)
#pragma unroll
      for (int q = 0; q < 4; q++) {
        int m = m0 + wr * 64 + i * 16 + (l >> 4) * 4 + q;
#pragma unroll
        for (int j = 0; j < 4; j++) {
          int n = n0 + wc * 64 + j * 16 + (l & 15);
          if (n < Nc) C[(size_t)m * ldc + n] = acc[i][j][q];
        }
      }
  } else {
    __syncthreads();
    float* sp = (float*)lds;
#pragma unroll
    for (int i = 0; i < 4; i++)
#pragma unroll
      for (int q = 0; q < 4; q++) {
        float va = -3.0e38f, vb = -3.0e38f;
        int ja = 0, jb = 0;
#pragma unroll
        for (int j = 0; j < 4; j++) {
          float v = acc[i][j][q];
          if (v > vb) {
            if (v > va) { vb = va; jb = ja; va = v; ja = j; }
            else { vb = v; jb = j; }
          }
        }
        int row = wr * 64 + i * 16 + (l >> 4) * 4 + q;
        int contrib = wc * 16 + (l & 15);
        sp[(row * 32 + contrib) * 2] =
            __uint_as_float((__float_as_uint(va) & ~3u) | (unsigned)ja);
        sp[(row * 32 + contrib) * 2 + 1] =
            __uint_as_float((__float_as_uint(vb) & ~3u) | (unsigned)jb);
      }
    __syncthreads();
    if (t < 128) {
      int grow = m0 + t;
      if (grow < Mv) {
        float w0v = -3.0e38f, w1v = -3.0e38f, w2v = -3.0e38f, w3v = -3.0e38f;
        int d0 = 0, d1 = 0, d2 = 0, d3 = 0;
        for (int cbt = 0; cbt < 64; cbt++) {
          float v = sp[t * 64 + cbt];
          int contrib = cbt >> 1;
          int j = (int)(__float_as_uint(v) & 3u);
          int col = n0 + (contrib >> 4) * 64 + j * 16 + (contrib & 15);
          INS4(v, col);
        }
        size_t pb = (size_t)grow * 32 + chunk * 4;
        pi4[pb] = d0; pi4[pb + 1] = d1; pi4[pb + 2] = d2; pi4[pb + 3] = d3;
      }
    }
  }
}

// ---- exact fp32 rescore -> top-3 intents; fused e1 computation + intent counting ----
__global__ __launch_bounds__(256) void k_rescore(const int* __restrict__ pi4,
                                                 const float* __restrict__ item_w,
                                                 const float* __restrict__ Gt,
                                                 const float* __restrict__ intw,
                                                 const float* __restrict__ la,
                                                 int* __restrict__ idx3,
                                                 float* __restrict__ e1vals,
                                                 int* __restrict__ cnt, int M) {
  int r = (blockIdx.x * 256 + threadIdx.x) >> 6;
  int l = threadIdx.x & 63;
  if (r >= M) return;
  float2 iw = ((const float2*)(item_w + (size_t)r * 128))[l];
  float v0 = -3.0e38f, v1 = -3.0e38f, v2 = -3.0e38f;
  int c0 = 0, c1i = 0, c2 = 0;
  for (int s = 0; s < 32; s++) {
    int c = pi4[(size_t)r * 32 + s];
    float2 g = ((const float2*)(Gt + (size_t)c * 128))[l];
    float d = iw.x * g.x + iw.y * g.y;
#pragma unroll
    for (int o = 32; o; o >>= 1) d += __shfl_xor(d, o, 64);
    INS3(d, c);
  }
  float2 lav = ((const float2*)la)[l];
  float e1v[3];
  int cs[3] = {c0, c1i, c2};
#pragma unroll
  for (int k = 0; k < 3; k++) {
    float2 cw = ((const float2*)(intw + (size_t)cs[k] * 128))[l];
    float d = iw.x * (cw.x * lav.x) + iw.y * (cw.y * lav.y);
#pragma unroll
    for (int o = 32; o; o >>= 1) d += __shfl_xor(d, o, 64);
    e1v[k] = d >= 0.f ? d : 0.2f * d;
  }
  if (l == 0) {
    idx3[r * 3] = c0; idx3[r * 3 + 1] = c1i; idx3[r * 3 + 2] = c2;
    e1vals[r * 3] = e1v[0]; e1vals[r * 3 + 1] = e1v[1]; e1vals[r * 3 + 2] = e1v[2];
    atomicAdd(&cnt[c0], 1); atomicAdd(&cnt[c1i], 1); atomicAdd(&cnt[c2], 1);
  }
}

__global__ __launch_bounds__(1024) void k_scan(const int* __restrict__ cnt,
                                               int* __restrict__ offs,
                                               int* __restrict__ cur) {
  __shared__ int s[1024];
  int t = threadIdx.x;
  int own = cnt[t];
  s[t] = own;
  __syncthreads();
  for (int o = 1; o < 1024; o <<= 1) {
    int v = (t >= o) ? s[t - o] : 0;
    __syncthreads();
    s[t] += v;
    __syncthreads();
  }
  int excl = s[t] - own;
  offs[t] = excl;
  cur[t] = excl;
  if (t == 1023) offs[1024] = s[1023];
}

__global__ void k_scatter(const int* __restrict__ idx3, int* __restrict__ cur,
                          int* __restrict__ edge_id, int E) {
  int e = blockIdx.x * 256 + threadIdx.x;
  if (e < E) {
    int c = idx3[e];
    int pos = atomicAdd(&cur[c], 1);
    edge_id[pos] = e;
  }
}

// ---------------- per-intent softmax-weighted item gather (single pass) ----------------
__global__ __launch_bounds__(512) void k_intent(const float* __restrict__ item_w,
                                                const float* __restrict__ e1vals,
                                                const int* __restrict__ offs,
                                                const int* __restrict__ edge_id,
                                                float* __restrict__ intent_new) {
  int c = blockIdx.x;
  int start = offs[c], end = offs[c + 1];
  int t = threadIdx.x, lane = t & 63, w = t >> 6;
  __shared__ float smx[8], sden[8], sacc[8][128];
  float mx = -3.0e38f;
  for (int e = start + t; e < end; e += 512) mx = fmaxf(mx, e1vals[edge_id[e]]);
#pragma unroll
  for (int o = 32; o; o >>= 1) mx = fmaxf(mx, __shfl_xor(mx, o, 64));
  if (lane == 0) smx[w] = mx;
  __syncthreads();
  mx = smx[0];
#pragma unroll
  for (int i = 1; i < 8; i++) mx = fmaxf(mx, smx[i]);
  float ax = 0.f, ay = 0.f, den = 0.f;
  int e = start + w;
  for (; e + 24 < end; e += 32) {
    int e0 = edge_id[e], e1 = edge_id[e + 8], e2 = edge_id[e + 16], e3 = edge_id[e + 24];
    float2 r0 = ((const float2*)(item_w + (size_t)((unsigned)e0 / 3u) * 128))[lane];
    float2 r1 = ((const float2*)(item_w + (size_t)((unsigned)e1 / 3u) * 128))[lane];
    float2 r2 = ((const float2*)(item_w + (size_t)((unsigned)e2 / 3u) * 128))[lane];
    float2 r3 = ((const float2*)(item_w + (size_t)((unsigned)e3 / 3u) * 128))[lane];
    float w0 = expf(e1vals[e0] - mx), w1 = expf(e1vals[e1] - mx);
    float w2 = expf(e1vals[e2] - mx), w3 = expf(e1vals[e3] - mx);
    ax = fmaf(w0, r0.x, fmaf(w1, r1.x, fmaf(w2, r2.x, fmaf(w3, r3.x, ax))));
    ay = fmaf(w0, r0.y, fmaf(w1, r1.y, fmaf(w2, r2.y, fmaf(w3, r3.y, ay))));
    den += w0 + w1 + w2 + w3;
  }
  for (; e < end; e += 8) {
    int e0 = edge_id[e];
    float2 r0 = ((const float2*)(item_w + (size_t)((unsigned)e0 / 3u) * 128))[lane];
    float w0 = expf(e1vals[e0] - mx);
    ax = fmaf(w0, r0.x, ax);
    ay = fmaf(w0, r0.y, ay);
    den += w0;
  }
  sacc[w][2 * lane] = ax;
  sacc[w][2 * lane + 1] = ay;
  if (lane == 0) sden[w] = den;
  __syncthreads();
  if (t < 128) {
    float s = 0.f;
#pragma unroll
    for (int i = 0; i < 8; i++) s += sacc[i][t];
    float dt = 0.f;
#pragma unroll
    for (int i = 0; i < 8; i++) dt += sden[i];
    float inv = dt > 0.f ? 1.f / dt : 0.f;
    intent_new[(size_t)c * 128 + t] = s * inv;
  }
}

// ---------------- h_intent for the referenced (b,n) items ----------------
__global__ __launch_bounds__(256) void k_hintent(const int* __restrict__ items,
                                                 const float* __restrict__ item_w,
                                                 const int* __restrict__ idx3,
                                                 const float* __restrict__ intent_new,
                                                 const float* __restrict__ lb,
                                                 float* __restrict__ h_intent, int total) {
  int g = (blockIdx.x * 256 + threadIdx.x) >> 6;
  int lane = threadIdx.x & 63;
  if (g >= total) return;
  int it = items[g];
  float2 iw = ((const float2*)(item_w + (size_t)it * 128))[lane];
  float2 lbv = ((const float2*)lb)[lane];
  float e2[3];
  float2 nb[3];
#pragma unroll
  for (int k = 0; k < 3; k++) {
    int c = idx3[(size_t)it * 3 + k];
    nb[k] = ((const float2*)(intent_new + (size_t)c * 128))[lane];
    float d = iw.x * nb[k].x * lbv.x + iw.y * nb[k].y * lbv.y;
#pragma unroll
    for (int o = 32; o; o >>= 1) d += __shfl_xor(d, o, 64);
    e2[k] = d >= 0.f ? d : 0.2f * d;
  }
  float m = fmaxf(fmaxf(e2[0], e2[1]), e2[2]);
  float x0 = expf(e2[0] - m), x1 = expf(e2[1] - m), x2 = expf(e2[2] - m);
  float inv = 1.f / (x0 + x1 + x2);
  float nx = (x0 * nb[0].x + x1 * nb[1].x + x2 * nb[2].x) * inv;
  float ny = (x0 * nb[0].y + x1 * nb[1].y + x2 * nb[2].y) * inv;
  ((float2*)(h_intent + (size_t)g * 128))[lane] =
      make_float2(0.5f * iw.x + 0.5f * nx, 0.5f * iw.y + 0.5f * ny);
}

// ---------------- fused per-session local graph + readout -> hf ----------------
// lane = j-column layout: no per-(i,j) shuffle chains; hiT transposed LDS copy.
__global__ __launch_bounds__(512) void k_session(
    const int* __restrict__ items, const int* __restrict__ Aadj,
    const int* __restrict__ inputs, const int* __restrict__ masks,
    const int* __restrict__ alias_inp, const float* __restrict__ item_w,
    const float* __restrict__ pos_emb, const float* __restrict__ la1,
    const float* __restrict__ la2, const float* __restrict__ lb1,
    const float* __restrict__ lb2, const float* __restrict__ W1,
    const float* __restrict__ b1, const float* __restrict__ W2,
    const float* __restrict__ b2, const float* __restrict__ w3,
    const float* __restrict__ h_intent, float* __restrict__ hf_out) {
  const int b = blockIdx.x;
  const int t = threadIdx.x;
  const int lane = t & 63, w = t >> 6;
  __shared__ float hi[50][128];      // item rows -> later sessions
  __shared__ float outb[6400];       // hiT[128][50] during attention; output rows after
  __shared__ float attb[2504];       // att[50][50]; tmp4[4][128] & wred[8][13] time-overlaid
  __shared__ float hsb[128], hsrb[128], q2b[128];
  __shared__ float cj1v[50], cj2v[50], alb[50];
  __shared__ float4 lab[128];        // (la1, la2, lb1, lb2)

  float* hiT = outb;
  float* att = attb;
  float* tmp4 = attb;        // [4][128], phases without att live
  float* wred = attb + 512;  // [8][13], q1 phase (att dead)

  float mfs = 0.f;
  for (int l = 0; l < 50; l++) mfs += (float)masks[b * 50 + l];

  // gather hi rows + la/lb staging + hs partials
  for (int i = t; i < 50 * 32; i += 512) {
    int r = i >> 5, c4 = (i & 31) << 2;
    int it = items[b * 50 + r];
    *(float4*)&hi[r][c4] = *(const float4*)(item_w + (size_t)it * 128 + c4);
  }
  if (t < 128) lab[t] = make_float4(la1[t], la2[t], lb1[t], lb2[t]);
  {
    int d = t & 127, g = t >> 7;
    float acc = 0.f;
    for (int l = g; l < 50; l += 4) {
      float m = (float)masks[b * 50 + l];
      int row = inputs[b * 50 + l];
      acc += m * item_w[(size_t)row * 128 + d];
    }
    tmp4[g * 128 + d] = acc;
  }
  __syncthreads();
  if (t < 128) hsb[t] = (tmp4[t] + tmp4[128 + t] + tmp4[256 + t] + tmp4[384 + t]) / mfs;
  // build hiT (reads hi, ready)
  for (int i = t; i < 6400; i += 512) {
    int r = i >> 7, d = i & 127;
    hiT[d * 50 + r] = hi[r][d];
  }
  __syncthreads();
  // cj1/cj2: lane j over d (wave 0 only)
  if (w == 0) {
    int jc = lane < 50 ? lane : 49;
    float s1 = 0.f, s2 = 0.f;
#pragma unroll 8
    for (int d = 0; d < 128; d++) {
      float xj = hiT[d * 50 + jc];
      float4 c = lab[d];
      float hv = hsb[d];
      s1 = fmaf(hv * c.z, xj, s1);
      s2 = fmaf(hv * c.w, xj, s2);
    }
    if (lane < 50) { cj1v[lane] = s1; cj2v[lane] = s2; }
  }
  __syncthreads();
  // attention scores + softmax, row i per wave, lane = j
  for (int i = w; i < 50; i += 8) {
    int jc = lane < 50 ? lane : 49;
    float s1 = 0.f, s2 = 0.f;
#pragma unroll 8
    for (int d = 0; d < 128; d++) {
      float xi = hiT[d * 50 + i];
      float4 c = lab[d];
      float xj = hiT[d * 50 + jc];
      s1 = fmaf(xi * c.x, xj, s1);
      s2 = fmaf(xi * c.y, xj, s2);
    }
    float v = -9e15f;
    if (lane < 50) {
      int a = Aadj[((size_t)b * 50 + i) * 50 + lane];
      if (a == 1) { float x = s1 + cj1v[lane]; v = x >= 0.f ? x : 0.2f * x; }
      else if (a == 2) { float x = s2 + cj2v[lane]; v = x >= 0.f ? x : 0.2f * x; }
    }
    float mx = v;
#pragma unroll
    for (int o = 32; o; o >>= 1) mx = fmaxf(mx, __shfl_xor(mx, o, 64));
    float ex = lane < 50 ? expf(v - mx) : 0.f;
    float sm = ex;
#pragma unroll
    for (int o = 32; o; o >>= 1) sm += __shfl_xor(sm, o, 64);
    if (lane < 50) att[i * 50 + lane] = ex / sm;
  }
  __syncthreads();  // att done; hiT dead
  // h_local + combine with h_intent -> outb rows
  for (int i = w; i < 50; i += 8) {
    float ax = 0.f, ay = 0.f;
    for (int j = 0; j < 50; j++) {
      float a = att[i * 50 + j];
      float2 xj = *(const float2*)&hi[j][2 * lane];
      ax = fmaf(a, xj.x, ax);
      ay = fmaf(a, xj.y, ay);
    }
    float2 hv = ((const float2*)(h_intent + ((size_t)b * 50 + i) * 128))[lane];
    *(float2*)&outb[i * 128 + 2 * lane] =
        make_float2(ax + hv.x + ax * hv.x, ay + hv.y + ay * hv.y);
  }
  __syncthreads();
  // sessions gather into hi
  for (int i = t; i < 50 * 64; i += 512) {
    int r = i >> 6, c2 = (i & 63) << 1;
    int a = alias_inp[b * 50 + r];
    *(float2*)&hi[r][c2] = *(const float2*)&outb[a * 128 + c2];
  }
  __syncthreads();
  // hir = sessions + pos -> outb
  for (int i = t; i < 50 * 64; i += 512) {
    int r = i >> 6, c2 = (i & 63) << 1;
    float2 s = *(const float2*)&hi[r][c2];
    float2 pp = *(const float2*)(pos_emb + (size_t)r * 128 + c2);
    *(float2*)&outb[r * 128 + c2] = make_float2(s.x + pp.x, s.y + pp.y);
  }
  __syncthreads();
  // hsr
  {
    int d = t & 127, g = t >> 7;
    float acc = 0.f;
    for (int l = g; l < 50; l += 4) acc += (float)masks[b * 50 + l] * outb[l * 128 + d];
    tmp4[g * 128 + d] = acc;
  }
  __syncthreads();
  if (t < 128) hsrb[t] = (tmp4[t] + tmp4[128 + t] + tmp4[256 + t] + tmp4[384 + t]) / mfs;
  __syncthreads();
  // q2 = hsr @ W2 + b2
  {
    int d = t & 127, g = t >> 7;
    float acc = 0.f;
    for (int k = g * 32; k < g * 32 + 32; k++)
      acc = fmaf(hsrb[k], W2[(size_t)k * 128 + d], acc);
    tmp4[g * 128 + d] = acc;
  }
  __syncthreads();
  if (t < 128) q2b[t] = b2[t] + tmp4[t] + tmp4[128 + t] + tmp4[256 + t] + tmp4[384 + t];
  __syncthreads();
  // q1 rows + al  (rows l = g + 4*jj, d-halves per wave pair)
  {
    int d = t & 127, g = t >> 7;
    float accq[13];
#pragma unroll
    for (int jj = 0; jj < 13; jj++) accq[jj] = b1[d];
    for (int k = 0; k < 128; k += 2) {
      float w1a = W1[(size_t)k * 128 + d];
      float w1b = W1[(size_t)(k + 1) * 128 + d];
#pragma unroll
      for (int jj = 0; jj < 13; jj++) {
        int l = g + 4 * jj;
        int le = l < 50 ? l : 0;
        float2 hv = *(const float2*)&outb[le * 128 + k];
        accq[jj] = fmaf(hv.x, w1a, accq[jj]);
        accq[jj] = fmaf(hv.y, w1b, accq[jj]);
      }
    }
    float w3v = w3[d], q2v = q2b[d];
#pragma unroll
    for (int jj = 0; jj < 13; jj++) {
      float s = 1.f / (1.f + expf(-(accq[jj] + q2v))) * w3v;
#pragma unroll
      for (int o = 32; o; o >>= 1) s += __shfl_xor(s, o, 64);
      if (lane == 0) wred[w * 13 + jj] = s;
    }
  }
  __syncthreads();
  if (t < 50) {
    int g = t & 3, jj = t >> 2;
    alb[t] = wred[(2 * g) * 13 + jj] + wred[(2 * g + 1) * 13 + jj];
  }
  __syncthreads();
  if (t < 128) {
    int d = t;
    float acc = 0.f, pacc = 0.f;
    for (int l = 0; l < 50; l++) {
      float m = (float)masks[b * 50 + l];
      acc += alb[l] * hi[l][d] * m;
      pacc += pos_emb[(size_t)l * 128 + d] * m;
    }
    hf_out[(size_t)b * 128 + d] = acc + pos_emb[50 * 128 + d] * (pacc / mfs);
  }
}

extern "C" void kernel_launch(void* const* d_in, const int* in_sizes, int n_in,
                              void* d_out, int out_size, void* d_ws, size_t ws_size,
                              hipStream_t stream) {
  const int* items = (const int*)d_in[0];
  const int* Aadj = (const int*)d_in[1];
  const int* inputs = (const int*)d_in[2];
  const int* masks = (const int*)d_in[3];
  const int* alias = (const int*)d_in[4];
  const float* item_emb = (const float*)d_in[5];
  const float* intent_emb = (const float*)d_in[6];
  const float* pos_emb = (const float*)d_in[7];
  const float* lq = (const float*)d_in[8];
  const float* lk = (const float*)d_in[9];
  const float* la = (const float*)d_in[10];
  const float* lb = (const float*)d_in[11];
  const float* la1 = (const float*)d_in[12];
  const float* la2 = (const float*)d_in[13];
  const float* lb1 = (const float*)d_in[14];
  const float* lb2 = (const float*)d_in[15];
  const float* W1 = (const float*)d_in[16];
  const float* b1 = (const float*)d_in[17];
  const float* W2 = (const float*)d_in[18];
  const float* b2 = (const float*)d_in[19];
  const float* w3 = (const float*)d_in[20];
  float* out = (float*)d_out;

  char* p = (char*)d_ws;
  auto alloc = [&](size_t bytes) {
    char* r = p;
    p += (bytes + 511) & ~(size_t)511;
    return r;
  };
  float* item_w = (float*)alloc(100000ull * 128 * 4);
  unsigned short* itp = (unsigned short*)alloc(100104ull * 384 * 2);
  unsigned short* gtp = (unsigned short*)alloc(1024ull * 384 * 2);
  float* intw = (float*)alloc(1024ull * 128 * 4);
  float* CK = (float*)alloc(1024ull * 128 * 4);
  float* Gt = (float*)alloc(1024ull * 128 * 4);
  float* lkT = (float*)alloc(128 * 128 * 4);
  int* idx3 = (int*)alloc(300000ull * 4);
  float* e1vals = (float*)alloc(300000ull * 4);
  int* cnt = (int*)alloc(1024 * 4);
  int* offs = (int*)alloc(1025 * 4);
  int* cur = (int*)alloc(1024 * 4);
  int* edge_id = (int*)alloc(300000ull * 4);
  char* big = alloc(13107200);  // overlay: pi4 (12.8MB) then h_int (13.1MB)
  int* pi4 = (int*)big;
  float* h_int = (float*)big;
  float* hf = (float*)alloc(512 * 128 * 4);
  float* hfp_f = (float*)alloc(512ull * 384 * 2);
  unsigned short* hfp = (unsigned short*)hfp_f;

  k_prep_item<<<25000, 256, 0, stream>>>(item_emb, item_w, itp, 100000);
  k_norm<<<256, 256, 0, stream>>>(intent_emb, intw, 1024);
  k_t128<<<1, 256, 0, stream>>>(lk, lkT);
  k_gemm_abt<<<dim3(3, 16), 256, 0, stream>>>(intw, lkT, CK, 1024, 128);
  k_gemm_abt<<<dim3(3, 16), 256, 0, stream>>>(CK, lq, Gt, 1024, 128);
  k_split<<<256, 256, 0, stream>>>(Gt, gtp, 1024);

  hipMemsetAsync(cnt, 0, 1024 * 4, stream);
  k_mfma<0><<<6272, 256, 0, stream>>>(itp, gtp, nullptr, 0, 1024, pi4, 100000);
  k_rescore<<<25000, 256, 0, stream>>>(pi4, item_w, Gt, intw, la, idx3, e1vals, cnt, 100000);

  k_scan<<<1, 1024, 0, stream>>>(cnt, offs, cur);
  k_scatter<<<(300000 + 255) / 256, 256, 0, stream>>>(idx3, cur, edge_id, 300000);
  k_intent<<<1024, 512, 0, stream>>>(item_w, e1vals, offs, edge_id, (float*)CK);
  k_hintent<<<6400, 256, 0, stream>>>(items, item_w, idx3, (float*)CK, lb, h_int, 25600);
  k_session<<<512, 512, 0, stream>>>(items, Aadj, inputs, masks, alias, item_w, pos_emb,
                                     la1, la2, lb1, lb2, W1, b1, W2, b2, w3, h_int, hf);
  k_split<<<128, 256, 0, stream>>>(hf, hfp, 512);
  k_mfma<1><<<3136, 256, 0, stream>>>(hfp, itp + 384, out, 99999, 99999, nullptr, 512);
}

// Round 6
// 1097.345 us; speedup vs baseline: 2.3421x; 1.0326x over previous
//
#include <hip/hip_runtime.h>
#include <math.h>

typedef __attribute__((ext_vector_type(4))) float f32x4;
typedef __attribute__((ext_vector_type(8))) short bf16x8;

static __device__ __forceinline__ unsigned short f2bf(float f) {
  unsigned int u = __float_as_uint(f);
  unsigned int r = (u + 0x7FFFu + ((u >> 16) & 1u)) >> 16;
  return (unsigned short)r;
}
static __device__ __forceinline__ float bf2f(unsigned short h) {
  return __uint_as_float(((unsigned int)h) << 16);
}

#define INS3(vv, cc) do { float _v=(vv); int _c=(cc); \
  if (_v > v2) { if (_v > v1) { v2=v1; c2=c1i; if (_v > v0) { v1=v0; c1i=c0; v0=_v; c0=_c; } \
  else { v1=_v; c1i=_c; } } else { v2=_v; c2=_c; } } } while(0)

#define INS4(vv, cc) do { float _v=(vv); int _c=(cc); \
  if (_v > w3v) { if (_v > w1v) { if (_v > w0v) { w3v=w2v;d3=d2; w2v=w1v;d2=d1; w1v=w0v;d1=d0; w0v=_v;d0=_c; } \
    else { w3v=w2v;d3=d2; w2v=w1v;d2=d1; w1v=_v;d1=_c; } } \
    else { if (_v > w2v) { w3v=w2v;d3=d2; w2v=_v;d2=_c; } else { w3v=_v; d3=_c; } } } } while(0)

// ---------------- intents: normalize ----------------
__global__ __launch_bounds__(256) void k_norm(const float* __restrict__ in,
                                              float* __restrict__ out, int R) {
  int g = (blockIdx.x * 256 + threadIdx.x) >> 6;
  int lane = threadIdx.x & 63;
  if (g >= R) return;
  float2 v = ((const float2*)(in + (size_t)g * 128))[lane];
  float ss = v.x * v.x + v.y * v.y;
#pragma unroll
  for (int o = 32; o; o >>= 1) ss += __shfl_xor(ss, o, 64);
  float s = 1.0f / sqrtf(ss);
  ((float2*)(out + (size_t)g * 128))[lane] = make_float2(v.x * s, v.y * s);
}

// ---------------- items: normalize + write fp32 + split [hi|hi|lo] ----------------
__global__ __launch_bounds__(256) void k_prep_item(const float* __restrict__ in,
                                                   float* __restrict__ item_w,
                                                   unsigned short* __restrict__ itp, int R) {
  int g = (blockIdx.x * 256 + threadIdx.x) >> 6;
  int lane = threadIdx.x & 63;
  if (g >= R) return;
  float2 v = ((const float2*)(in + (size_t)g * 128))[lane];
  float ss = v.x * v.x + v.y * v.y;
#pragma unroll
  for (int o = 32; o; o >>= 1) ss += __shfl_xor(ss, o, 64);
  float s = 1.0f / sqrtf(ss);
  float x = v.x * s, y = v.y * s;
  ((float2*)(item_w + (size_t)g * 128))[lane] = make_float2(x, y);
  unsigned short hx = f2bf(x), hy = f2bf(y);
  unsigned short lx = f2bf(x - bf2f(hx)), ly = f2bf(y - bf2f(hy));
  unsigned short* row = itp + (size_t)g * 384;
  ((ushort2*)row)[lane] = make_ushort2(hx, hy);
  ((ushort2*)(row + 128))[lane] = make_ushort2(hx, hy);
  ((ushort2*)(row + 256))[lane] = make_ushort2(lx, ly);
}

// ---------------- generic split [hi|lo|hi] ----------------
__global__ __launch_bounds__(256) void k_split(const float* __restrict__ in,
                                               unsigned short* __restrict__ outp, int R) {
  int g = (blockIdx.x * 256 + threadIdx.x) >> 6;
  int lane = threadIdx.x & 63;
  if (g >= R) return;
  float2 v = ((const float2*)(in + (size_t)g * 128))[lane];
  unsigned short hx = f2bf(v.x), hy = f2bf(v.y);
  unsigned short lx = f2bf(v.x - bf2f(hx)), ly = f2bf(v.y - bf2f(hy));
  unsigned short* row = outp + (size_t)g * 384;
  ((ushort2*)row)[lane] = make_ushort2(hx, hy);
  ((ushort2*)(row + 128))[lane] = make_ushort2(lx, ly);
  ((ushort2*)(row + 256))[lane] = make_ushort2(hx, hy);
}

// ---------------- 128x128 transpose ----------------
__global__ __launch_bounds__(256) void k_t128(const float* __restrict__ in,
                                              float* __restrict__ out) {
  for (int i = threadIdx.x; i < 128 * 128; i += 256) {
    int k = i >> 7, j = i & 127;
    out[j * 128 + k] = in[i];
  }
}

// ---------------- small fp32 C[MxN] = A[Mx128] @ B[Nx128]^T ----------------
__global__ __launch_bounds__(256) void k_gemm_abt(const float* __restrict__ A,
                                                  const float* __restrict__ B,
                                                  float* __restrict__ C, int M, int N) {
  __shared__ float As[64][132];
  __shared__ float Bs[48][132];
  const int t = threadIdx.x;
  const int m0 = blockIdx.y * 64, n0 = blockIdx.x * 48;
  for (int i = t; i < 64 * 32; i += 256) {
    int r = i >> 5, c4 = (i & 31) << 2;
    float4 v = make_float4(0.f, 0.f, 0.f, 0.f);
    if (m0 + r < M) v = *(const float4*)(A + (size_t)(m0 + r) * 128 + c4);
    *(float4*)&As[r][c4] = v;
  }
  for (int i = t; i < 48 * 32; i += 256) {
    int r = i >> 5, c4 = (i & 31) << 2;
    float4 v = make_float4(0.f, 0.f, 0.f, 0.f);
    if (n0 + r < N) v = *(const float4*)(B + (size_t)(n0 + r) * 128 + c4);
    *(float4*)&Bs[r][c4] = v;
  }
  __syncthreads();
  const int ty = t >> 4, tx = t & 15;
  float acc[4][3];
#pragma unroll
  for (int i = 0; i < 4; i++)
#pragma unroll
    for (int j = 0; j < 3; j++) acc[i][j] = 0.f;
#pragma unroll 4
  for (int k = 0; k < 128; k += 4) {
    float4 a[4], b[3];
#pragma unroll
    for (int i = 0; i < 4; i++) a[i] = *(const float4*)&As[ty + 16 * i][k];
#pragma unroll
    for (int j = 0; j < 3; j++) b[j] = *(const float4*)&Bs[tx + 16 * j][k];
#pragma unroll
    for (int i = 0; i < 4; i++)
#pragma unroll
      for (int j = 0; j < 3; j++) {
        float s = acc[i][j];
        s = fmaf(a[i].x, b[j].x, s);
        s = fmaf(a[i].y, b[j].y, s);
        s = fmaf(a[i].z, b[j].z, s);
        s = fmaf(a[i].w, b[j].w, s);
        acc[i][j] = s;
      }
  }
#pragma unroll
  for (int i = 0; i < 4; i++) {
    int m = m0 + ty + 16 * i;
    if (m >= M) continue;
#pragma unroll
    for (int j = 0; j < 3; j++) {
      int n = n0 + tx + 16 * j;
      if (n < N) C[(size_t)m * N + n] = acc[i][j];
    }
  }
}

// ---------------- MFMA split-bf16 GEMM: C[M x N] = A[M x 384] @ B[N x 384]^T ----------------
template <int MODE>
__global__ __launch_bounds__(256, 2) void k_mfma(const unsigned short* __restrict__ Abase,
                                                 const unsigned short* __restrict__ Bbase,
                                                 float* __restrict__ C, int ldc, int Nc,
                                                 int* __restrict__ pi4, int Mv) {
  __shared__ __align__(16) char lds[32768];
  const int t = threadIdx.x, l = t & 63, w = t >> 6;
  const int wr = w >> 1, wc = w & 1;

  int m0, n0, chunk = 0;
  {
    int g = blockIdx.x;
    int xcd = g & 7, r = g >> 3;
    if (MODE == 0) {
      chunk = r & 7;
      int mt = (r >> 3) * 8 + xcd;
      if (mt >= ((Mv + 127) >> 7)) return;
      m0 = mt << 7;
      n0 = chunk << 7;
    } else {
      int mq = r & 3;
      int nt = (r >> 2) * 8 + xcd;
      if (nt >= ((Nc + 127) >> 7)) return;
      m0 = mq << 7;
      n0 = nt << 7;
    }
  }
  const unsigned short* A = Abase + (size_t)m0 * 384;
  const unsigned short* B = Bbase + (size_t)n0 * 384;

  const int r1 = t >> 2, c1 = t & 3;
  f32x4 acc[4][4];
  {
    f32x4 z = {0.f, 0.f, 0.f, 0.f};
#pragma unroll
    for (int i = 0; i < 4; i++)
#pragma unroll
      for (int j = 0; j < 4; j++) acc[i][j] = z;
  }

  int4 sa0, sa1, sb0, sb1;
  {
    sa0 = *(const int4*)(A + (size_t)r1 * 384 + c1 * 8);
    sa1 = *(const int4*)(A + (size_t)(r1 + 64) * 384 + c1 * 8);
    sb0 = *(const int4*)(B + (size_t)r1 * 384 + c1 * 8);
    sb1 = *(const int4*)(B + (size_t)(r1 + 64) * 384 + c1 * 8);
  }

  for (int kt = 0; kt < 12; ++kt) {
    if (kt) __syncthreads();
    *(int4*)(lds + r1 * 80 + c1 * 16) = sa0;
    *(int4*)(lds + (r1 + 64) * 80 + c1 * 16) = sa1;
    *(int4*)(lds + 10240 + r1 * 80 + c1 * 16) = sb0;
    *(int4*)(lds + 10240 + (r1 + 64) * 80 + c1 * 16) = sb1;
    __syncthreads();
    if (kt < 11) {
      const unsigned short* ka = A + (kt + 1) * 32;
      const unsigned short* kb = B + (kt + 1) * 32;
      sa0 = *(const int4*)(ka + (size_t)r1 * 384 + c1 * 8);
      sa1 = *(const int4*)(ka + (size_t)(r1 + 64) * 384 + c1 * 8);
      sb0 = *(const int4*)(kb + (size_t)r1 * 384 + c1 * 8);
      sb1 = *(const int4*)(kb + (size_t)(r1 + 64) * 384 + c1 * 8);
    }
    bf16x8 af[4], bfr[4];
#pragma unroll
    for (int i = 0; i < 4; i++) {
      int ar = wr * 64 + i * 16 + (l & 15);
      af[i] = *(const bf16x8*)(lds + ar * 80 + (l >> 4) * 16);
      int br = wc * 64 + i * 16 + (l & 15);
      bfr[i] = *(const bf16x8*)(lds + 10240 + br * 80 + (l >> 4) * 16);
    }
#pragma unroll
    for (int i = 0; i < 4; i++)
#pragma unroll
      for (int j = 0; j < 4; j++)
        acc[i][j] = __builtin_amdgcn_mfma_f32_16x16x32_bf16(af[i], bfr[j], acc[i][j], 0, 0, 0);
  }

  if (MODE == 1) {
#pragma unroll
    for (int i = 0; i < 4; i++)
#pragma unroll
      for (int q = 0; q < 4; q++) {
        int m = m0 + wr * 64 + i * 16 + (l >> 4) * 4 + q;
#pragma unroll
        for (int j = 0; j < 4; j++) {
          int n = n0 + wc * 64 + j * 16 + (l & 15);
          if (n < Nc) C[(size_t)m * ldc + n] = acc[i][j][q];
        }
      }
  } else {
    __syncthreads();
    float* sp = (float*)lds;
#pragma unroll
    for (int i = 0; i < 4; i++)
#pragma unroll
      for (int q = 0; q < 4; q++) {
        float va = -3.0e38f, vb = -3.0e38f;
        int ja = 0, jb = 0;
#pragma unroll
        for (int j = 0; j < 4; j++) {
          float v = acc[i][j][q];
          if (v > vb) {
            if (v > va) { vb = va; jb = ja; va = v; ja = j; }
            else { vb = v; jb = j; }
          }
        }
        int row = wr * 64 + i * 16 + (l >> 4) * 4 + q;
        int contrib = wc * 16 + (l & 15);
        sp[(row * 32 + contrib) * 2] =
            __uint_as_float((__float_as_uint(va) & ~3u) | (unsigned)ja);
        sp[(row * 32 + contrib) * 2 + 1] =
            __uint_as_float((__float_as_uint(vb) & ~3u) | (unsigned)jb);
      }
    __syncthreads();
    if (t < 128) {
      int grow = m0 + t;
      if (grow < Mv) {
        float w0v = -3.0e38f, w1v = -3.0e38f, w2v = -3.0e38f, w3v = -3.0e38f;
        int d0 = 0, d1 = 0, d2 = 0, d3 = 0;
        for (int cbt = 0; cbt < 64; cbt++) {
          float v = sp[t * 64 + cbt];
          int contrib = cbt >> 1;
          int j = (int)(__float_as_uint(v) & 3u);
          int col = n0 + (contrib >> 4) * 64 + j * 16 + (contrib & 15);
          INS4(v, col);
        }
        size_t pb = (size_t)grow * 32 + chunk * 4;
        pi4[pb] = d0; pi4[pb + 1] = d1; pi4[pb + 2] = d2; pi4[pb + 3] = d3;
      }
    }
  }
}

// ---- exact fp32 rescore -> top-3; lane-local dots (no shuffles), 8 rows/block ----
__global__ __launch_bounds__(256) void k_rescore(const int* __restrict__ pi4,
                                                 const float* __restrict__ item_w,
                                                 const float* __restrict__ Gt,
                                                 const float* __restrict__ intw,
                                                 const float* __restrict__ la,
                                                 int* __restrict__ idx3,
                                                 float* __restrict__ e1vals,
                                                 int* __restrict__ cnt, int M) {
  __shared__ float iwS[8][128];
  __shared__ float laS[128];
  __shared__ float sval[8][32];
  __shared__ int scol[8][32];
  __shared__ int sc3[8][3];
  const int t = threadIdx.x;
  const int rbase = blockIdx.x * 8;
  {
    int row = t >> 5, c4 = (t & 31) << 2;
    int gr = rbase + row;
    float4 v = make_float4(0.f, 0.f, 0.f, 0.f);
    if (gr < M) v = *(const float4*)(item_w + (size_t)gr * 128 + c4);
    *(float4*)&iwS[row][c4] = v;
  }
  if (t < 32) ((float4*)laS)[t] = ((const float4*)la)[t];
  __syncthreads();
  const int row = t >> 5, s = t & 31;
  const int gr = rbase + row;
  float val = -3.0e38f;
  int col = 0;
  if (gr < M) {
    col = pi4[(size_t)gr * 32 + s];
    const float4* g4 = (const float4*)(Gt + (size_t)col * 128);
    float a0 = 0.f, a1 = 0.f, a2 = 0.f, a3 = 0.f;
#pragma unroll
    for (int d4 = 0; d4 < 32; d4 += 4) {
      float4 x0 = *(const float4*)&iwS[row][d4 * 4];
      float4 y0 = g4[d4];
      float4 x1 = *(const float4*)&iwS[row][d4 * 4 + 4];
      float4 y1 = g4[d4 + 1];
      float4 x2 = *(const float4*)&iwS[row][d4 * 4 + 8];
      float4 y2 = g4[d4 + 2];
      float4 x3 = *(const float4*)&iwS[row][d4 * 4 + 12];
      float4 y3 = g4[d4 + 3];
      a0 = fmaf(x0.x, y0.x, fmaf(x0.y, y0.y, fmaf(x0.z, y0.z, fmaf(x0.w, y0.w, a0))));
      a1 = fmaf(x1.x, y1.x, fmaf(x1.y, y1.y, fmaf(x1.z, y1.z, fmaf(x1.w, y1.w, a1))));
      a2 = fmaf(x2.x, y2.x, fmaf(x2.y, y2.y, fmaf(x2.z, y2.z, fmaf(x2.w, y2.w, a2))));
      a3 = fmaf(x3.x, y3.x, fmaf(x3.y, y3.y, fmaf(x3.z, y3.z, fmaf(x3.w, y3.w, a3))));
    }
    val = (a0 + a1) + (a2 + a3);
  }
  sval[row][s] = val;
  scol[row][s] = col;
  __syncthreads();
  if (t < 8) {
    int grr = rbase + t;
    if (grr < M) {
      float v0 = -3.0e38f, v1 = -3.0e38f, v2 = -3.0e38f;
      int c0 = 0, c1i = 0, c2 = 0;
      for (int s2 = 0; s2 < 32; s2++) INS3(sval[t][s2], scol[t][s2]);
      idx3[grr * 3] = c0; idx3[grr * 3 + 1] = c1i; idx3[grr * 3 + 2] = c2;
      sc3[t][0] = c0; sc3[t][1] = c1i; sc3[t][2] = c2;
      atomicAdd(&cnt[c0], 1); atomicAdd(&cnt[c1i], 1); atomicAdd(&cnt[c2], 1);
    }
  }
  __syncthreads();
  if (gr < M && s < 3) {
    int c = sc3[row][s];
    const float4* cw = (const float4*)(intw + (size_t)c * 128);
    float acc = 0.f;
#pragma unroll
    for (int d4 = 0; d4 < 32; d4++) {
      float4 a = *(const float4*)&iwS[row][d4 * 4];
      float4 lv = *(const float4*)&laS[d4 * 4];
      float4 b = cw[d4];
      acc = fmaf(a.x * lv.x, b.x,
            fmaf(a.y * lv.y, b.y, fmaf(a.z * lv.z, b.z, fmaf(a.w * lv.w, b.w, acc))));
    }
    e1vals[gr * 3 + s] = acc >= 0.f ? acc : 0.2f * acc;
  }
}

__global__ __launch_bounds__(1024) void k_scan(const int* __restrict__ cnt,
                                               int* __restrict__ offs,
                                               int* __restrict__ cur) {
  __shared__ int s[1024];
  int t = threadIdx.x;
  int own = cnt[t];
  s[t] = own;
  __syncthreads();
  for (int o = 1; o < 1024; o <<= 1) {
    int v = (t >= o) ? s[t - o] : 0;
    __syncthreads();
    s[t] += v;
    __syncthreads();
  }
  int excl = s[t] - own;
  offs[t] = excl;
  cur[t] = excl;
  if (t == 1023) offs[1024] = s[1023];
}

__global__ void k_scatter(const int* __restrict__ idx3, int* __restrict__ cur,
                          int* __restrict__ edge_id, int E) {
  int e = blockIdx.x * 256 + threadIdx.x;
  if (e < E) {
    int c = idx3[e];
    int pos = atomicAdd(&cur[c], 1);
    edge_id[pos] = e;
  }
}

// ---------------- per-intent softmax-weighted item gather (single pass) ----------------
__global__ __launch_bounds__(512) void k_intent(const float* __restrict__ item_w,
                                                const float* __restrict__ e1vals,
                                                const int* __restrict__ offs,
                                                const int* __restrict__ edge_id,
                                                float* __restrict__ intent_new) {
  int c = blockIdx.x;
  int start = offs[c], end = offs[c + 1];
  int t = threadIdx.x, lane = t & 63, w = t >> 6;
  __shared__ float smx[8], sden[8], sacc[8][128];
  float mx = -3.0e38f;
  for (int e = start + t; e < end; e += 512) mx = fmaxf(mx, e1vals[edge_id[e]]);
#pragma unroll
  for (int o = 32; o; o >>= 1) mx = fmaxf(mx, __shfl_xor(mx, o, 64));
  if (lane == 0) smx[w] = mx;
  __syncthreads();
  mx = smx[0];
#pragma unroll
  for (int i = 1; i < 8; i++) mx = fmaxf(mx, smx[i]);
  float ax = 0.f, ay = 0.f, den = 0.f;
  int e = start + w;
  for (; e + 24 < end; e += 32) {
    int e0 = edge_id[e], e1 = edge_id[e + 8], e2 = edge_id[e + 16], e3 = edge_id[e + 24];
    float2 r0 = ((const float2*)(item_w + (size_t)((unsigned)e0 / 3u) * 128))[lane];
    float2 r1 = ((const float2*)(item_w + (size_t)((unsigned)e1 / 3u) * 128))[lane];
    float2 r2 = ((const float2*)(item_w + (size_t)((unsigned)e2 / 3u) * 128))[lane];
    float2 r3 = ((const float2*)(item_w + (size_t)((unsigned)e3 / 3u) * 128))[lane];
    float w0 = expf(e1vals[e0] - mx), w1 = expf(e1vals[e1] - mx);
    float w2 = expf(e1vals[e2] - mx), w3 = expf(e1vals[e3] - mx);
    ax = fmaf(w0, r0.x, fmaf(w1, r1.x, fmaf(w2, r2.x, fmaf(w3, r3.x, ax))));
    ay = fmaf(w0, r0.y, fmaf(w1, r1.y, fmaf(w2, r2.y, fmaf(w3, r3.y, ay))));
    den += w0 + w1 + w2 + w3;
  }
  for (; e < end; e += 8) {
    int e0 = edge_id[e];
    float2 r0 = ((const float2*)(item_w + (size_t)((unsigned)e0 / 3u) * 128))[lane];
    float w0 = expf(e1vals[e0] - mx);
    ax = fmaf(w0, r0.x, ax);
    ay = fmaf(w0, r0.y, ay);
    den += w0;
  }
  sacc[w][2 * lane] = ax;
  sacc[w][2 * lane + 1] = ay;
  if (lane == 0) sden[w] = den;
  __syncthreads();
  if (t < 128) {
    float s = 0.f;
#pragma unroll
    for (int i = 0; i < 8; i++) s += sacc[i][t];
    float dt = 0.f;
#pragma unroll
    for (int i = 0; i < 8; i++) dt += sden[i];
    float inv = dt > 0.f ? 1.f / dt : 0.f;
    intent_new[(size_t)c * 128 + t] = s * inv;
  }
}

// ---------------- h_intent for the referenced (b,n) items ----------------
__global__ __launch_bounds__(256) void k_hintent(const int* __restrict__ items,
                                                 const float* __restrict__ item_w,
                                                 const int* __restrict__ idx3,
                                                 const float* __restrict__ intent_new,
                                                 const float* __restrict__ lb,
                                                 float* __restrict__ h_intent, int total) {
  int g = (blockIdx.x * 256 + threadIdx.x) >> 6;
  int lane = threadIdx.x & 63;
  if (g >= total) return;
  int it = items[g];
  float2 iw = ((const float2*)(item_w + (size_t)it * 128))[lane];
  float2 lbv = ((const float2*)lb)[lane];
  float e2[3];
  float2 nb[3];
#pragma unroll
  for (int k = 0; k < 3; k++) {
    int c = idx3[(size_t)it * 3 + k];
    nb[k] = ((const float2*)(intent_new + (size_t)c * 128))[lane];
    float d = iw.x * nb[k].x * lbv.x + iw.y * nb[k].y * lbv.y;
#pragma unroll
    for (int o = 32; o; o >>= 1) d += __shfl_xor(d, o, 64);
    e2[k] = d >= 0.f ? d : 0.2f * d;
  }
  float m = fmaxf(fmaxf(e2[0], e2[1]), e2[2]);
  float x0 = expf(e2[0] - m), x1 = expf(e2[1] - m), x2 = expf(e2[2] - m);
  float inv = 1.f / (x0 + x1 + x2);
  float nx = (x0 * nb[0].x + x1 * nb[1].x + x2 * nb[2].x) * inv;
  float ny = (x0 * nb[0].y + x1 * nb[1].y + x2 * nb[2].y) * inv;
  ((float2*)(h_intent + (size_t)g * 128))[lane] =
      make_float2(0.5f * iw.x + 0.5f * nx, 0.5f * iw.y + 0.5f * ny);
}

// ---------------- fused per-session local graph + readout -> hf ----------------
__global__ __launch_bounds__(512) void k_session(
    const int* __restrict__ items, const int* __restrict__ Aadj,
    const int* __restrict__ inputs, const int* __restrict__ masks,
    const int* __restrict__ alias_inp, const float* __restrict__ item_w,
    const float* __restrict__ pos_emb, const float* __restrict__ la1,
    const float* __restrict__ la2, const float* __restrict__ lb1,
    const float* __restrict__ lb2, const float* __restrict__ W1,
    const float* __restrict__ b1, const float* __restrict__ W2,
    const float* __restrict__ b2, const float* __restrict__ w3,
    const float* __restrict__ h_intent, float* __restrict__ hf_out) {
  const int b = blockIdx.x;
  const int t = threadIdx.x;
  const int lane = t & 63, w = t >> 6;
  __shared__ float hi[50][128];
  __shared__ float outb[6400];
  __shared__ float attb[2504];
  __shared__ float hsb[128], hsrb[128], q2b[128];
  __shared__ float cj1v[50], cj2v[50], alb[50];
  __shared__ float4 lab[128];

  float* hiT = outb;
  float* att = attb;
  float* tmp4 = attb;
  float* wred = attb + 512;

  float mfs = 0.f;
  for (int l = 0; l < 50; l++) mfs += (float)masks[b * 50 + l];

  for (int i = t; i < 50 * 32; i += 512) {
    int r = i >> 5, c4 = (i & 31) << 2;
    int it = items[b * 50 + r];
    *(float4*)&hi[r][c4] = *(const float4*)(item_w + (size_t)it * 128 + c4);
  }
  if (t < 128) lab[t] = make_float4(la1[t], la2[t], lb1[t], lb2[t]);
  {
    int d = t & 127, g = t >> 7;
    float acc = 0.f;
    for (int l = g; l < 50; l += 4) {
      float m = (float)masks[b * 50 + l];
      int row = inputs[b * 50 + l];
      acc += m * item_w[(size_t)row * 128 + d];
    }
    tmp4[g * 128 + d] = acc;
  }
  __syncthreads();
  if (t < 128) hsb[t] = (tmp4[t] + tmp4[128 + t] + tmp4[256 + t] + tmp4[384 + t]) / mfs;
  for (int i = t; i < 6400; i += 512) {
    int r = i >> 7, d = i & 127;
    hiT[d * 50 + r] = hi[r][d];
  }
  __syncthreads();
  if (w == 0) {
    int jc = lane < 50 ? lane : 49;
    float s1 = 0.f, s2 = 0.f;
#pragma unroll 8
    for (int d = 0; d < 128; d++) {
      float xj = hiT[d * 50 + jc];
      float4 c = lab[d];
      float hv = hsb[d];
      s1 = fmaf(hv * c.z, xj, s1);
      s2 = fmaf(hv * c.w, xj, s2);
    }
    if (lane < 50) { cj1v[lane] = s1; cj2v[lane] = s2; }
  }
  __syncthreads();
  for (int i = w; i < 50; i += 8) {
    int jc = lane < 50 ? lane : 49;
    float s1 = 0.f, s2 = 0.f;
#pragma unroll 8
    for (int d = 0; d < 128; d++) {
      float xi = hiT[d * 50 + i];
      float4 c = lab[d];
      float xj = hiT[d * 50 + jc];
      s1 = fmaf(xi * c.x, xj, s1);
      s2 = fmaf(xi * c.y, xj, s2);
    }
    float v = -9e15f;
    if (lane < 50) {
      int a = Aadj[((size_t)b * 50 + i) * 50 + lane];
      if (a == 1) { float x = s1 + cj1v[lane]; v = x >= 0.f ? x : 0.2f * x; }
      else if (a == 2) { float x = s2 + cj2v[lane]; v = x >= 0.f ? x : 0.2f * x; }
    }
    float mx = v;
#pragma unroll
    for (int o = 32; o; o >>= 1) mx = fmaxf(mx, __shfl_xor(mx, o, 64));
    float ex = lane < 50 ? expf(v - mx) : 0.f;
    float sm = ex;
#pragma unroll
    for (int o = 32; o; o >>= 1) sm += __shfl_xor(sm, o, 64);
    if (lane < 50) att[i * 50 + lane] = ex / sm;
  }
  __syncthreads();
  for (int i = w; i < 50; i += 8) {
    float ax = 0.f, ay = 0.f;
    for (int j = 0; j < 50; j++) {
      float a = att[i * 50 + j];
      float2 xj = *(const float2*)&hi[j][2 * lane];
      ax = fmaf(a, xj.x, ax);
      ay = fmaf(a, xj.y, ay);
    }
    float2 hv = ((const float2*)(h_intent + ((size_t)b * 50 + i) * 128))[lane];
    *(float2*)&outb[i * 128 + 2 * lane] =
        make_float2(ax + hv.x + ax * hv.x, ay + hv.y + ay * hv.y);
  }
  __syncthreads();
  for (int i = t; i < 50 * 64; i += 512) {
    int r = i >> 6, c2 = (i & 63) << 1;
    int a = alias_inp[b * 50 + r];
    *(float2*)&hi[r][c2] = *(const float2*)&outb[a * 128 + c2];
  }
  __syncthreads();
  for (int i = t; i < 50 * 64; i += 512) {
    int r = i >> 6, c2 = (i & 63) << 1;
    float2 s = *(const float2*)&hi[r][c2];
    float2 pp = *(const float2*)(pos_emb + (size_t)r * 128 + c2);
    *(float2*)&outb[r * 128 + c2] = make_float2(s.x + pp.x, s.y + pp.y);
  }
  __syncthreads();
  {
    int d = t & 127, g = t >> 7;
    float acc = 0.f;
    for (int l = g; l < 50; l += 4) acc += (float)masks[b * 50 + l] * outb[l * 128 + d];
    tmp4[g * 128 + d] = acc;
  }
  __syncthreads();
  if (t < 128) hsrb[t] = (tmp4[t] + tmp4[128 + t] + tmp4[256 + t] + tmp4[384 + t]) / mfs;
  __syncthreads();
  {
    int d = t & 127, g = t >> 7;
    float acc = 0.f;
    for (int k = g * 32; k < g * 32 + 32; k++)
      acc = fmaf(hsrb[k], W2[(size_t)k * 128 + d], acc);
    tmp4[g * 128 + d] = acc;
  }
  __syncthreads();
  if (t < 128) q2b[t] = b2[t] + tmp4[t] + tmp4[128 + t] + tmp4[256 + t] + tmp4[384 + t];
  __syncthreads();
  {
    int d = t & 127, g = t >> 7;
    float accq[13];
#pragma unroll
    for (int jj = 0; jj < 13; jj++) accq[jj] = b1[d];
    for (int k = 0; k < 128; k += 2) {
      float w1a = W1[(size_t)k * 128 + d];
      float w1b = W1[(size_t)(k + 1) * 128 + d];
#pragma unroll
      for (int jj = 0; jj < 13; jj++) {
        int l = g + 4 * jj;
        int le = l < 50 ? l : 0;
        float2 hv = *(const float2*)&outb[le * 128 + k];
        accq[jj] = fmaf(hv.x, w1a, accq[jj]);
        accq[jj] = fmaf(hv.y, w1b, accq[jj]);
      }
    }
    float w3v = w3[d], q2v = q2b[d];
#pragma unroll
    for (int jj = 0; jj < 13; jj++) {
      float s = 1.f / (1.f + expf(-(accq[jj] + q2v))) * w3v;
#pragma unroll
      for (int o = 32; o; o >>= 1) s += __shfl_xor(s, o, 64);
      if (lane == 0) wred[w * 13 + jj] = s;
    }
  }
  __syncthreads();
  if (t < 50) {
    int g = t & 3, jj = t >> 2;
    alb[t] = wred[(2 * g) * 13 + jj] + wred[(2 * g + 1) * 13 + jj];
  }
  __syncthreads();
  if (t < 128) {
    int d = t;
    float acc = 0.f, pacc = 0.f;
    for (int l = 0; l < 50; l++) {
      float m = (float)masks[b * 50 + l];
      acc += alb[l] * hi[l][d] * m;
      pacc += pos_emb[(size_t)l * 128 + d] * m;
    }
    hf_out[(size_t)b * 128 + d] = acc + pos_emb[50 * 128 + d] * (pacc / mfs);
  }
}

extern "C" void kernel_launch(void* const* d_in, const int* in_sizes, int n_in,
                              void* d_out, int out_size, void* d_ws, size_t ws_size,
                              hipStream_t stream) {
  const int* items = (const int*)d_in[0];
  const int* Aadj = (const int*)d_in[1];
  const int* inputs = (const int*)d_in[2];
  const int* masks = (const int*)d_in[3];
  const int* alias = (const int*)d_in[4];
  const float* item_emb = (const float*)d_in[5];
  const float* intent_emb = (const float*)d_in[6];
  const float* pos_emb = (const float*)d_in[7];
  const float* lq = (const float*)d_in[8];
  const float* lk = (const float*)d_in[9];
  const float* la = (const float*)d_in[10];
  const float* lb = (const float*)d_in[11];
  const float* la1 = (const float*)d_in[12];
  const float* la2 = (const float*)d_in[13];
  const float* lb1 = (const float*)d_in[14];
  const float* lb2 = (const float*)d_in[15];
  const float* W1 = (const float*)d_in[16];
  const float* b1 = (const float*)d_in[17];
  const float* W2 = (const float*)d_in[18];
  const float* b2 = (const float*)d_in[19];
  const float* w3 = (const float*)d_in[20];
  float* out = (float*)d_out;

  char* p = (char*)d_ws;
  auto alloc = [&](size_t bytes) {
    char* r = p;
    p += (bytes + 511) & ~(size_t)511;
    return r;
  };
  float* item_w = (float*)alloc(100000ull * 128 * 4);
  unsigned short* itp = (unsigned short*)alloc(100104ull * 384 * 2);
  unsigned short* gtp = (unsigned short*)alloc(1024ull * 384 * 2);
  float* intw = (float*)alloc(1024ull * 128 * 4);
  float* CK = (float*)alloc(1024ull * 128 * 4);
  float* Gt = (float*)alloc(1024ull * 128 * 4);
  float* lkT = (float*)alloc(128 * 128 * 4);
  int* idx3 = (int*)alloc(300000ull * 4);
  float* e1vals = (float*)alloc(300000ull * 4);
  int* cnt = (int*)alloc(1024 * 4);
  int* offs = (int*)alloc(1025 * 4);
  int* cur = (int*)alloc(1024 * 4);
  int* edge_id = (int*)alloc(300000ull * 4);
  char* big = alloc(13107200);  // overlay: pi4 (12.8MB) then h_int (13.1MB)
  int* pi4 = (int*)big;
  float* h_int = (float*)big;
  float* hf = (float*)alloc(512 * 128 * 4);
  float* hfp_f = (float*)alloc(512ull * 384 * 2);
  unsigned short* hfp = (unsigned short*)hfp_f;

  k_prep_item<<<25000, 256, 0, stream>>>(item_emb, item_w, itp, 100000);
  k_norm<<<256, 256, 0, stream>>>(intent_emb, intw, 1024);
  k_t128<<<1, 256, 0, stream>>>(lk, lkT);
  k_gemm_abt<<<dim3(3, 16), 256, 0, stream>>>(intw, lkT, CK, 1024, 128);
  k_gemm_abt<<<dim3(3, 16), 256, 0, stream>>>(CK, lq, Gt, 1024, 128);
  k_split<<<256, 256, 0, stream>>>(Gt, gtp, 1024);

  hipMemsetAsync(cnt, 0, 1024 * 4, stream);
  k_mfma<0><<<6272, 256, 0, stream>>>(itp, gtp, nullptr, 0, 1024, pi4, 100000);
  k_rescore<<<12500, 256, 0, stream>>>(pi4, item_w, Gt, intw, la, idx3, e1vals, cnt, 100000);

  k_scan<<<1, 1024, 0, stream>>>(cnt, offs, cur);
  k_scatter<<<(300000 + 255) / 256, 256, 0, stream>>>(idx3, cur, edge_id, 300000);
  k_intent<<<1024, 512, 0, stream>>>(item_w, e1vals, offs, edge_id, (float*)CK);
  k_hintent<<<6400, 256, 0, stream>>>(items, item_w, idx3, (float*)CK, lb, h_int, 25600);
  k_session<<<512, 512, 0, stream>>>(items, Aadj, inputs, masks, alias, item_w, pos_emb,
                                     la1, la2, lb1, lb2, W1, b1, W2, b2, w3, h_int, hf);
  k_split<<<128, 256, 0, stream>>>(hf, hfp, 512);
  k_mfma<1><<<3136, 256, 0, stream>>>(hfp, itp + 384, out, 99999, 99999, nullptr, 512);
}